// Round 7
// baseline (279.204 us; speedup 1.0000x reference)
//
#include <hip/hip_runtime.h>

#define Bz 8
#define Sz 2048
#define Ez 512
#define Hz 8
#define Dz 64

typedef _Float16 f16;
typedef __attribute__((ext_vector_type(2))) _Float16 f16x2;
typedef __attribute__((ext_vector_type(8))) _Float16 f16x8;
typedef __attribute__((ext_vector_type(4))) float f32x4;

#define LOG2E 1.44269504f

__device__ __forceinline__ void async16(const void* g, void* l) {
    __builtin_amdgcn_global_load_lds(
        (const __attribute__((address_space(1))) unsigned int*)g,
        (__attribute__((address_space(3))) unsigned int*)l, 16, 0, 0);
}

__device__ __forceinline__ f16x2 pkrtz(float a, float b) {
    return __builtin_bit_cast(f16x2, __builtin_amdgcn_cvt_pkrtz(a, b));
}

__device__ __forceinline__ int swz(int row) {
    return (row & 7) ^ ((2 * ((row >> 3) & 3)) & 7);
}

// ===========================================================================
// cast: blocks 0..2047 -> grid-stride fp32->f16 cast of q/k/v (32B load +
// 16B store per iteration, 6 iters/thread -- BW-shaped per m13 pattern).
// blocks 2048..2055 -> mask compaction (idx/slen) + vt rank-pad zero-fill.
// ===========================================================================
__global__ __launch_bounds__(256)
void cast_kernel(const float* __restrict__ q, const float* __restrict__ k,
                 const float* __restrict__ v, const int* __restrict__ mask,
                 f16* __restrict__ qa, f16* __restrict__ ka, f16* __restrict__ va,
                 int* __restrict__ idx, int* __restrict__ slen, f16* __restrict__ vt)
{
    const int blk = blockIdx.x;
    const int tid = threadIdx.x;
    if (blk >= 2048) {
        const int b = blk - 2048;
        if (b >= Bz) return;
        __shared__ int sc2[2][256];
        __shared__ int ssl;
        const int* mp = mask + (size_t)b * Sz;
        int m[8], c = 0;
        #pragma unroll
        for (int j = 0; j < 8; ++j) { m[j] = mp[tid*8 + j]; c += (m[j] == 0); }
        sc2[0][tid] = c;
        __syncthreads();
        int src = 0;
        #pragma unroll
        for (int s = 1; s < 256; s <<= 1) {
            int vv = sc2[src][tid] + ((tid >= s) ? sc2[src][tid - s] : 0);
            sc2[src ^ 1][tid] = vv;
            src ^= 1;
            __syncthreads();
        }
        int incl = sc2[src][tid];
        int base = incl - c;
        if (tid == 255) { slen[b] = incl; ssl = incl; }
        int kk = base;
        #pragma unroll
        for (int j = 0; j < 8; ++j)
            if (m[j] == 0) idx[(size_t)b * Sz + (kk++)] = tid*8 + j;
        __syncthreads();
        const int sl2 = ssl;
        const int pad = (sl2 + 63) & ~63;
        if (pad > sl2) {
            for (int pr = tid; pr < Hz * Dz; pr += 256) {
                f16* dst = vt + ((size_t)b * Hz * Dz + pr) * Sz;
                for (int j = sl2; j < pad; ++j) dst[j] = (f16)0.f;
            }
        }
        return;
    }
    // grid-stride cast: chunk = 8 fp32 -> 8 f16. nAct/8 = 2^20 chunks/tensor.
    const unsigned CPT = 1u << 20;            // chunks per tensor
    for (unsigned c = blk * 256 + tid; c < 3 * CPT; c += 2048 * 256) {
        const unsigned z = c >> 20;
        const size_t off = (size_t)(c & (CPT - 1)) * 8;
        const float* s = (z == 0) ? q : (z == 1) ? k : v;
        f16* dst = (z == 0) ? qa : (z == 1) ? ka : va;
        float4 x0 = *(const float4*)&s[off];
        float4 x1 = *(const float4*)&s[off + 4];
        f16 h[8];
        f16x2 p0 = pkrtz(x0.x, x0.y), p1 = pkrtz(x0.z, x0.w);
        f16x2 p2 = pkrtz(x1.x, x1.y), p3 = pkrtz(x1.z, x1.w);
        h[0] = p0[0]; h[1] = p0[1]; h[2] = p1[0]; h[3] = p1[1];
        h[4] = p2[0]; h[5] = p2[1]; h[6] = p3[0]; h[7] = p3[1];
        *(uint4*)&dst[off] = *(uint4*)h;
    }
}

// ===========================================================================
// prep_w: W fp32 [k][n] -> Wt f16 [n][k]; z==0 (wq) scaled by 0.125*log2e
// ===========================================================================
__global__ __launch_bounds__(256)
void prep_w(const float* __restrict__ W0, const float* __restrict__ W1,
            const float* __restrict__ W2, const float* __restrict__ W3,
            f16* __restrict__ T0, f16* __restrict__ T1,
            f16* __restrict__ T2, f16* __restrict__ T3)
{
    __shared__ float S[64][68];
    const float* W = (blockIdx.z==0)?W0:(blockIdx.z==1)?W1:(blockIdx.z==2)?W2:W3;
    f16*         T = (blockIdx.z==0)?T0:(blockIdx.z==1)?T1:(blockIdx.z==2)?T2:T3;
    const float sc = (blockIdx.z == 0) ? 0.125f * LOG2E : 1.0f;
    const int k0 = blockIdx.x * 64, n0 = blockIdx.y * 64;
    const int tid = threadIdx.x;
    {
        int kr = tid >> 4, nc = (tid & 15) * 4;
        #pragma unroll
        for (int i = 0; i < 4; ++i) {
            float4 w4 = *(const float4*)&W[(size_t)(k0 + kr + i*16) * Ez + n0 + nc];
            S[kr + i*16][nc+0] = w4.x; S[kr + i*16][nc+1] = w4.y;
            S[kr + i*16][nc+2] = w4.z; S[kr + i*16][nc+3] = w4.w;
        }
    }
    __syncthreads();
    {
        int n = tid >> 2, kq = tid & 3;
        f16 h[16];
        #pragma unroll
        for (int j = 0; j < 16; ++j) h[j] = (f16)(S[kq*16 + j][n] * sc);
        f16* dst = &T[(size_t)(n0 + n) * Ez + k0 + kq*16];
        *(uint4*)&dst[0] = *(uint4*)&h[0];
        *(uint4*)&dst[8] = *(uint4*)&h[8];
    }
}

// ===========================================================================
// proj_gemm: DOUBLE-buffered DMA staging, 128x128 tile, BK=32.
// z picks {q,k,v}.
//  z==0: full M=16384; Q rows -> qp (B,H,S,D).
//  z==1/2: A rows GATHERED by rank (per-lane global_load_lds source =
//    activation row idx[b][rank]); M shrinks to slen[b] per b, blocks past
//    slen early-exit. K rows -> kp dense-by-rank. V staged TRANSPOSED in
//    LDS (Tr2[d][m]) then uint4 row-reads + uint4 rank-run stores into vt
//    (B,H,D,Sz) -- fully vectorized, no gap scatter.
//  Tail ranks (>= slen) use clamped source rows; K garbage is zeroed
//  post-exp in attn, V stores are predicated < slen (cast pre-zeroed pad).
// ===========================================================================
__global__ __launch_bounds__(256, 4)
void proj_gemm(const f16* __restrict__ qa, const f16* __restrict__ ka,
               const f16* __restrict__ va,
               const f16* __restrict__ wtq, const f16* __restrict__ wtk,
               const f16* __restrict__ wtv,
               const float* __restrict__ bqp, const float* __restrict__ bkp,
               const float* __restrict__ bvp, const int* __restrict__ idx,
               const int* __restrict__ slen,
               f16* __restrict__ qp, f16* __restrict__ kp, f16* __restrict__ vt)
{
    __shared__ __align__(16) char lds[32768];
    const int z = blockIdx.z;
    const int m0 = blockIdx.x * 128, n0 = blockIdx.y * 128;
    const int bb = m0 >> 11;
    const int m0c = m0 & (Sz - 1);

    int sl = Sz;
    if (z != 0) {
        sl = slen[bb];
        if (m0c >= sl) return;      // uniform early-exit: tile fully past slen
    }

    const f16* A  = (z==0)?qa:(z==1)?ka:va;
    const f16* Wt = (z==0)?wtq:(z==1)?wtk:wtv;
    const float* bias = (z==0)?bqp:(z==1)?bkp:bvp;
    const float bscale = (z==0) ? 0.125f*LOG2E : 1.0f;

    const int tid  = threadIdx.x;
    const int lane = tid & 63, w = tid >> 6;
    const int col  = lane & 15, quad = lane >> 4;
    const int wm = w & 1, wn = w >> 1;
    const int srow = lane >> 2, schunk = lane & 3;

    // per-thread staging source row bases (rank-gathered for K/V)
    size_t rb[2];
    int clv[2];
    #pragma unroll
    for (int i = 0; i < 2; ++i) {
        const int row = w*32 + i*16 + srow;
        clv[i] = schunk ^ ((row >> 1) & 3);
        const int j = m0c + row;
        int srcrow;
        if (z == 0) {
            srcrow = j;
        } else {
            const int jc = (j < sl) ? j : sl - 1;
            srcrow = idx[(size_t)bb * Sz + jc];
        }
        rb[i] = ((size_t)bb * Sz + srcrow) * Ez;
    }

    f32x4 acc[4][4];
    #pragma unroll
    for (int i = 0; i < 4; ++i)
        #pragma unroll
        for (int j = 0; j < 4; ++j) acc[i][j] = (f32x4){0.f,0.f,0.f,0.f};

    auto issue = [&](int t, int buf) {
        f16* As = (f16*)(lds + buf * 16384);
        f16* Ws = As + 4096;
        #pragma unroll
        for (int i = 0; i < 2; ++i) {
            const int row = w*32 + i*16 + srow;
            async16(&A[rb[i] + t*32 + clv[i]*8],                    &As[row*32 + schunk*8]);
            async16(&Wt[(size_t)(n0 + row) * Ez + t*32 + clv[i]*8], &Ws[row*32 + schunk*8]);
        }
    };

    issue(0, 0);
    const int xrc = (col >> 1) & 3;

    for (int t = 0; t < 16; ++t) {
        const int cur = t & 1;
        __syncthreads();
        if (t < 15) issue(t + 1, cur ^ 1);
        f16* As = (f16*)(lds + cur * 16384);
        f16* Ws = As + 4096;
        f16x8 af[4];
        #pragma unroll
        for (int mi = 0; mi < 4; ++mi)
            af[mi] = *(const f16x8*)&As[(wm*64 + mi*16 + col)*32 + ((quad ^ xrc)*8)];
        #pragma unroll
        for (int ni = 0; ni < 4; ++ni) {
            f16x8 wf = *(const f16x8*)&Ws[(wn*64 + ni*16 + col)*32 + ((quad ^ xrc)*8)];
            #pragma unroll
            for (int mi = 0; mi < 4; ++mi)
                acc[mi][ni] = __builtin_amdgcn_mfma_f32_16x16x32_f16(af[mi], wf, acc[mi][ni], 0,0,0);
        }
    }

    const int rw = tid >> 1, half = tid & 1;

    f16* Tr  = (f16*)lds;    // z<2:  [128][72] row-major (m, d)
    f16* Tr2 = (f16*)lds;    // z==2: [64][136] transposed (d, m); 136*2=272, 16B rows
    #pragma unroll
    for (int p = 0; p < 2; ++p) {
        __syncthreads();
        if (wn == p) {
            #pragma unroll
            for (int ni = 0; ni < 4; ++ni) {
                float bv = bias[n0 + p*64 + ni*16 + col] * bscale;
                #pragma unroll
                for (int mi = 0; mi < 4; ++mi)
                    #pragma unroll
                    for (int rr = 0; rr < 4; ++rr) {
                        const int ml = wm*64 + mi*16 + quad*4 + rr;
                        const float val = acc[mi][ni][rr] + bv;
                        if (z != 2) Tr[ml*72 + ni*16 + col] = (f16)val;
                        else        Tr2[(ni*16 + col)*136 + ml] = (f16)val;
                    }
            }
        }
        __syncthreads();
        const int hh = (n0 >> 6) + p;
        if (z != 2) {
            const int rank = m0c + rw;
            if (z == 0 || rank < sl) {
                f16* C16 = (z == 0) ? qp : kp;
                f16* dst = &C16[(((size_t)bb*Hz + hh)*Sz + rank)*Dz + half*32];
                const f16* srcp = &Tr[rw*72 + half*32];
                #pragma unroll
                for (int j = 0; j < 4; ++j)
                    *(uint4*)&dst[j*8] = *(const uint4*)&srcp[j*8];
            }
        } else {
            const int d = tid >> 2, mq = tid & 3;
            const int base = m0c + mq*32;
            if (base < sl) {
                f16* dstb = vt + (((size_t)bb*Hz + hh)*Dz + d)*Sz + base;
                const f16* srcr = &Tr2[d*136 + mq*32];
                int lim = sl - base; if (lim > 32) lim = 32;
                if (lim == 32) {
                    #pragma unroll
                    for (int g = 0; g < 4; ++g)
                        *(uint4*)&dstb[g*8] = *(const uint4*)&srcr[g*8];
                } else {
                    const int full = lim >> 3;
                    for (int g = 0; g < full; ++g)
                        *(uint4*)&dstb[g*8] = *(const uint4*)&srcr[g*8];
                    for (int e = full*8; e < lim; ++e) dstb[e] = srcr[e];
                }
            }
        }
    }
}

// ===========================================================================
// out_gemm: DOUBLE-buffered staging, 128x128 tile, fp32 row-major + bias.
// ===========================================================================
__global__ __launch_bounds__(256, 4)
void out_gemm(const f16* __restrict__ A, const f16* __restrict__ Wt,
              const float* __restrict__ bias, float* __restrict__ Cf)
{
    __shared__ __align__(16) char lds[32768];
    const int tid  = threadIdx.x;
    const int lane = tid & 63, w = tid >> 6;
    const int col  = lane & 15, quad = lane >> 4;
    const int wm = w & 1, wn = w >> 1;
    const int m0 = blockIdx.x * 128, n0 = blockIdx.y * 128;
    const int srow = lane >> 2, schunk = lane & 3;

    f32x4 acc[4][4];
    #pragma unroll
    for (int i = 0; i < 4; ++i)
        #pragma unroll
        for (int j = 0; j < 4; ++j) acc[i][j] = (f32x4){0.f,0.f,0.f,0.f};

    auto issue = [&](int t, int buf) {
        f16* As = (f16*)(lds + buf * 16384);
        f16* Ws = As + 4096;
        #pragma unroll
        for (int i = 0; i < 2; ++i) {
            int row = w*32 + i*16 + srow;
            int cl = schunk ^ ((row >> 1) & 3);
            async16(&A[(size_t)(m0 + row) * Ez + t*32 + cl*8],  &As[row*32 + schunk*8]);
            async16(&Wt[(size_t)(n0 + row) * Ez + t*32 + cl*8], &Ws[row*32 + schunk*8]);
        }
    };

    issue(0, 0);
    const int xrc = (col >> 1) & 3;

    for (int t = 0; t < 16; ++t) {
        const int cur = t & 1;
        __syncthreads();
        if (t < 15) issue(t + 1, cur ^ 1);
        f16* As = (f16*)(lds + cur * 16384);
        f16* Ws = As + 4096;
        f16x8 af[4];
        #pragma unroll
        for (int mi = 0; mi < 4; ++mi)
            af[mi] = *(const f16x8*)&As[(wm*64 + mi*16 + col)*32 + ((quad ^ xrc)*8)];
        #pragma unroll
        for (int ni = 0; ni < 4; ++ni) {
            f16x8 wf = *(const f16x8*)&Ws[(wn*64 + ni*16 + col)*32 + ((quad ^ xrc)*8)];
            #pragma unroll
            for (int mi = 0; mi < 4; ++mi)
                acc[mi][ni] = __builtin_amdgcn_mfma_f32_16x16x32_f16(af[mi], wf, acc[mi][ni], 0,0,0);
        }
    }

    #pragma unroll
    for (int ni = 0; ni < 4; ++ni) {
        int n = n0 + wn*64 + ni*16 + col;
        float bv = bias[n];
        #pragma unroll
        for (int mi = 0; mi < 4; ++mi)
            #pragma unroll
            for (int rr = 0; rr < 4; ++rr) {
                int m = m0 + wm*64 + mi*16 + quad*4 + rr;
                Cf[(size_t)m * Ez + n] = acc[mi][ni][rr] + bv;
            }
    }
}

// ===========================================================================
// Flash attention over compacted keys (R2 structure: double-buffer +
// __syncthreads drain; 32KB LDS, 4 blocks/CU -- the occupancy IS the
// latency hiding, per R3's regression). K pre-compacted; V pre-transposed
// and pad-zeroed, so tail P-zeroing keeps everything exact.
// ===========================================================================
__global__ __launch_bounds__(256, 4)
void attn_f16(const f16* __restrict__ Q, const f16* __restrict__ K,
              const f16* __restrict__ VT, const int* __restrict__ slen,
              f16* __restrict__ O)
{
    __shared__ __align__(16) f16 KS[2][64*64];
    __shared__ __align__(16) f16 VS[2][64*64];

    const int tid  = threadIdx.x;
    const int lane = tid & 63, w = tid >> 6;
    const int col  = lane & 15, quad = lane >> 4;

    const int blk = blockIdx.x;
    const int xcd = blk & 7, slot = blk >> 3;
    const int bh = xcd + 8 * (slot >> 4);
    const int qb = slot & 15;
    const int b = bh >> 3, h = bh & 7;

    const int sl = slen[b];
    int nt = (sl + 63) >> 6;
    if (nt < 1) nt = 1;

    const int q0 = qb * 128 + w * 32;

    f16x8 qf[2][2];
    #pragma unroll
    for (int qt = 0; qt < 2; ++qt)
        #pragma unroll
        for (int ks = 0; ks < 2; ++ks)
            qf[qt][ks] = *(const f16x8*)&Q[((size_t)bh*Sz + q0 + qt*16 + col)*Dz + ks*32 + quad*8];

    const f16* Kp = K + (size_t)bh * Sz * Dz;
    const f16* Vp = VT + (size_t)bh * Dz * Sz;

    const int srow = lane >> 3, sch = lane & 7;
    const int row0 = w*16 + srow, row1 = row0 + 8;
    const int cl0 = sch ^ swz(row0), cl1 = sch ^ swz(row1);

    int keyrow[4], gk[4];
    #pragma unroll
    for (int kc = 0; kc < 4; ++kc) {
        keyrow[kc] = 32*(kc>>1) + 8*(col>>2) + 4*(kc&1) + (col&3);
        gk[kc] = swz(keyrow[kc]);
    }

    f32x4 oacc[2][4];
    #pragma unroll
    for (int qt = 0; qt < 2; ++qt)
        #pragma unroll
        for (int dc = 0; dc < 4; ++dc) oacc[qt][dc] = (f32x4){0.f,0.f,0.f,0.f};
    const f32x4 zero4 = (f32x4){0.f, 0.f, 0.f, 0.f};
    f32x4 lacc[2] = {(f32x4){0.f,0.f,0.f,0.f}, (f32x4){0.f,0.f,0.f,0.f}};
    f16x8 one8;
    #pragma unroll
    for (int i = 0; i < 8; ++i) one8[i] = (f16)1.0f;

    auto issue = [&](int t, int buf) {
        async16(&Kp[(size_t)(t*64 + row0)*Dz + cl0*8], &KS[buf][row0*64 + sch*8]);
        async16(&Vp[(size_t)row0*Sz + t*64 + cl0*8],   &VS[buf][row0*64 + sch*8]);
        async16(&Kp[(size_t)(t*64 + row1)*Dz + cl1*8], &KS[buf][row1*64 + sch*8]);
        async16(&Vp[(size_t)row1*Sz + t*64 + cl1*8],   &VS[buf][row1*64 + sch*8]);
    };

    issue(0, 0);

    for (int t = 0; t < nt; ++t) {
        const int cur = t & 1;
        __syncthreads();
        if (t + 1 < nt) issue(t + 1, cur ^ 1);

        // ---- QK^T: S^T = K·Q^T (C initialized from persistent zero regs)
        f32x4 sc[2][4];
        __builtin_amdgcn_s_setprio(1);
        #pragma unroll
        for (int kc = 0; kc < 4; ++kc) {
            f16x8 kf0 = *(const f16x8*)&KS[cur][keyrow[kc]*64 + ((quad ^ gk[kc])*8)];
            f16x8 kf1 = *(const f16x8*)&KS[cur][keyrow[kc]*64 + (((4 + quad) ^ gk[kc])*8)];
            sc[0][kc] = __builtin_amdgcn_mfma_f32_16x16x32_f16(kf0, qf[0][0], zero4, 0,0,0);
            sc[1][kc] = __builtin_amdgcn_mfma_f32_16x16x32_f16(kf0, qf[1][0], zero4, 0,0,0);
            sc[0][kc] = __builtin_amdgcn_mfma_f32_16x16x32_f16(kf1, qf[0][1], sc[0][kc], 0,0,0);
            sc[1][kc] = __builtin_amdgcn_mfma_f32_16x16x32_f16(kf1, qf[1][1], sc[1][kc], 0,0,0);
        }
        __builtin_amdgcn_s_setprio(0);

        // ---- p = exp2(s) (raw v_exp_f32); zero tail on last tile; pack B-frags
        const bool last = (t == nt - 1);
        union { f16x2 h2[4]; f16x8 h8; } ph[2][2];
        #pragma unroll
        for (int qt = 0; qt < 2; ++qt) {
            #pragma unroll
            for (int kg = 0; kg < 2; ++kg) {
                float e0 = __builtin_amdgcn_exp2f(sc[qt][2*kg][0]);
                float e1 = __builtin_amdgcn_exp2f(sc[qt][2*kg][1]);
                float e2 = __builtin_amdgcn_exp2f(sc[qt][2*kg][2]);
                float e3 = __builtin_amdgcn_exp2f(sc[qt][2*kg][3]);
                float e4 = __builtin_amdgcn_exp2f(sc[qt][2*kg+1][0]);
                float e5 = __builtin_amdgcn_exp2f(sc[qt][2*kg+1][1]);
                float e6 = __builtin_amdgcn_exp2f(sc[qt][2*kg+1][2]);
                float e7 = __builtin_amdgcn_exp2f(sc[qt][2*kg+1][3]);
                if (last) {
                    int rem = sl - t*64 - 32*kg - 8*quad;
                    e0 = (rem > 0) ? e0 : 0.f; e1 = (rem > 1) ? e1 : 0.f;
                    e2 = (rem > 2) ? e2 : 0.f; e3 = (rem > 3) ? e3 : 0.f;
                    e4 = (rem > 4) ? e4 : 0.f; e5 = (rem > 5) ? e5 : 0.f;
                    e6 = (rem > 6) ? e6 : 0.f; e7 = (rem > 7) ? e7 : 0.f;
                }
                ph[qt][kg].h2[0] = pkrtz(e0, e1);
                ph[qt][kg].h2[1] = pkrtz(e2, e3);
                ph[qt][kg].h2[2] = pkrtz(e4, e5);
                ph[qt][kg].h2[3] = pkrtz(e6, e7);
            }
        }

        // ---- lsum (ones-row MFMA) + PV: O^T += V^T·P^T
        __builtin_amdgcn_s_setprio(1);
        lacc[0] = __builtin_amdgcn_mfma_f32_16x16x32_f16(one8, ph[0][0].h8, lacc[0], 0,0,0);
        lacc[1] = __builtin_amdgcn_mfma_f32_16x16x32_f16(one8, ph[1][0].h8, lacc[1], 0,0,0);
        lacc[0] = __builtin_amdgcn_mfma_f32_16x16x32_f16(one8, ph[0][1].h8, lacc[0], 0,0,0);
        lacc[1] = __builtin_amdgcn_mfma_f32_16x16x32_f16(one8, ph[1][1].h8, lacc[1], 0,0,0);
        #pragma unroll
        for (int dc = 0; dc < 4; ++dc) {
            const int d = dc*16 + col;
            const int gd = swz(d);
            #pragma unroll
            for (int kg = 0; kg < 2; ++kg) {
                f16x8 vf = *(const f16x8*)&VS[cur][d*64 + (((kg*4 + quad) ^ gd)*8)];
                oacc[0][dc] = __builtin_amdgcn_mfma_f32_16x16x32_f16(vf, ph[0][kg].h8, oacc[0][dc], 0,0,0);
                oacc[1][dc] = __builtin_amdgcn_mfma_f32_16x16x32_f16(vf, ph[1][kg].h8, oacc[1][dc], 0,0,0);
            }
        }
        __builtin_amdgcn_s_setprio(0);
    }

    // lacc rows are identical (A = ones) -> no cross-lane reduce needed;
    // col = lane&15 matches oacc's query mapping.
    float inv[2];
    inv[0] = 1.0f / lacc[0][0];
    inv[1] = 1.0f / lacc[1][0];
    #pragma unroll
    for (int qt = 0; qt < 2; ++qt) {
        const int q = q0 + qt*16 + col;
        f16* op = &O[((size_t)b*Sz + q)*Ez + h*Dz];
        #pragma unroll
        for (int dc = 0; dc < 4; ++dc) {
            f16 ov[4] = {(f16)(oacc[qt][dc][0]*inv[qt]), (f16)(oacc[qt][dc][1]*inv[qt]),
                         (f16)(oacc[qt][dc][2]*inv[qt]), (f16)(oacc[qt][dc][3]*inv[qt])};
            *(uint2*)&op[dc*16 + quad*4] = *(uint2*)ov;
        }
    }
}

// ===========================================================================
extern "C" void kernel_launch(void* const* d_in, const int* in_sizes, int n_in,
                              void* d_out, int out_size, void* d_ws, size_t ws_size,
                              hipStream_t stream)
{
    const float* value = (const float*)d_in[0];
    const float* key   = (const float*)d_in[1];
    const float* query = (const float*)d_in[2];
    const int*   mask  = (const int*)d_in[3];
    const float* wq = (const float*)d_in[4];
    const float* bq = (const float*)d_in[5];
    const float* wk = (const float*)d_in[6];
    const float* bk = (const float*)d_in[7];
    const float* wv = (const float*)d_in[8];
    const float* bv = (const float*)d_in[9];
    const float* wo = (const float*)d_in[10];
    const float* bo = (const float*)d_in[11];
    float* out = (float*)d_out;

    const size_t nW   = (size_t)Ez * Ez;             // 262144
    const size_t nAct = (size_t)Bz * Sz * Ez;        // 8388608
    f16* wtq = (f16*)d_ws;
    f16* wtk = wtq + nW;
    f16* wtv = wtk + nW;
    f16* wto = wtv + nW;
    f16* qa  = wto + nW;
    f16* ka  = qa + nAct;
    f16* va  = ka + nAct;
    f16* qp  = va + nAct;
    f16* kp  = qp + nAct;
    f16* vt  = kp + nAct;
    f16* o16 = vt + nAct;
    int* idxp = (int*)(o16 + nAct);
    int* slenp = idxp + Bz * Sz;

    cast_kernel<<<2056, 256, 0, stream>>>(query, key, value, mask,
                                          qa, ka, va, idxp, slenp, vt);
    prep_w<<<dim3(8, 8, 4), 256, 0, stream>>>(wq, wk, wv, wo, wtq, wtk, wtv, wto);

    proj_gemm<<<dim3(128, 4, 3), 256, 0, stream>>>(qa, ka, va, wtq, wtk, wtv,
                                                   bq, bk, bv, idxp, slenp,
                                                   qp, kp, vt);

    attn_f16<<<1024, 256, 0, stream>>>(qp, kp, vt, slenp, o16);

    out_gemm<<<dim3(128, 4), 256, 0, stream>>>(o16, wto, bo, out);
}

// Round 8
// 275.671 us; speedup vs baseline: 1.0128x; 1.0128x over previous
//
#include <hip/hip_runtime.h>

#define Bz 8
#define Sz 2048
#define Ez 512
#define Hz 8
#define Dz 64

typedef _Float16 f16;
typedef __attribute__((ext_vector_type(2))) _Float16 f16x2;
typedef __attribute__((ext_vector_type(8))) _Float16 f16x8;
typedef __attribute__((ext_vector_type(4))) float f32x4;

#define LOG2E 1.44269504f

__device__ __forceinline__ void async16(const void* g, void* l) {
    __builtin_amdgcn_global_load_lds(
        (const __attribute__((address_space(1))) unsigned int*)g,
        (__attribute__((address_space(3))) unsigned int*)l, 16, 0, 0);
}

__device__ __forceinline__ f16x2 pkrtz(float a, float b) {
    return __builtin_bit_cast(f16x2, __builtin_amdgcn_cvt_pkrtz(a, b));
}

__device__ __forceinline__ int swz(int row) {
    return (row & 7) ^ ((2 * ((row >> 3) & 3)) & 7);
}

// ===========================================================================
// prep: blocks 0..255 -> weight transpose (W fp32 [k][n] -> Wt f16 [n][k],
// wq scaled by 0.125*log2e). blocks 256..263 -> mask scan: idx[b][j] = j-th
// unmasked key position, slen[b] = count; zero-fills vt rank-pad
// [slen, ceil64(slen)) so attn's PV never multiplies NaN garbage.
// ===========================================================================
__global__ __launch_bounds__(256)
void prep_kernel(const float* __restrict__ W0, const float* __restrict__ W1,
                 const float* __restrict__ W2, const float* __restrict__ W3,
                 f16* __restrict__ T0, f16* __restrict__ T1,
                 f16* __restrict__ T2, f16* __restrict__ T3,
                 const int* __restrict__ mask, int* __restrict__ idx,
                 int* __restrict__ slen, f16* __restrict__ vt)
{
    const int blk = blockIdx.x;
    const int tid = threadIdx.x;
    if (blk < 256) {
        __shared__ float S[64][68];
        const int z = blk >> 6, rest = blk & 63;
        const float* W = (z==0)?W0:(z==1)?W1:(z==2)?W2:W3;
        f16*         T = (z==0)?T0:(z==1)?T1:(z==2)?T2:T3;
        const float sc = (z == 0) ? 0.125f * LOG2E : 1.0f;
        const int k0 = (rest & 7) * 64, n0 = (rest >> 3) * 64;
        {
            int kr = tid >> 4, nc = (tid & 15) * 4;
            #pragma unroll
            for (int i = 0; i < 4; ++i) {
                float4 w4 = *(const float4*)&W[(size_t)(k0 + kr + i*16) * Ez + n0 + nc];
                S[kr + i*16][nc+0] = w4.x; S[kr + i*16][nc+1] = w4.y;
                S[kr + i*16][nc+2] = w4.z; S[kr + i*16][nc+3] = w4.w;
            }
        }
        __syncthreads();
        {
            int n = tid >> 2, kq = tid & 3;
            f16 h[16];
            #pragma unroll
            for (int j = 0; j < 16; ++j) h[j] = (f16)(S[kq*16 + j][n] * sc);
            f16* dst = &T[(size_t)(n0 + n) * Ez + k0 + kq*16];
            *(uint4*)&dst[0] = *(uint4*)&h[0];
            *(uint4*)&dst[8] = *(uint4*)&h[8];
        }
        return;
    }
    const int b = blk - 256;
    if (b >= Bz) return;
    __shared__ int sc2[2][256];
    __shared__ int ssl;
    const int* mp = mask + (size_t)b * Sz;
    int m[8], c = 0;
    #pragma unroll
    for (int j = 0; j < 8; ++j) { m[j] = mp[tid*8 + j]; c += (m[j] == 0); }
    sc2[0][tid] = c;
    __syncthreads();
    int src = 0;
    #pragma unroll
    for (int s = 1; s < 256; s <<= 1) {
        int vv = sc2[src][tid] + ((tid >= s) ? sc2[src][tid - s] : 0);
        sc2[src ^ 1][tid] = vv;
        src ^= 1;
        __syncthreads();
    }
    int incl = sc2[src][tid];
    int base = incl - c;
    if (tid == 255) { slen[b] = incl; ssl = incl; }
    int kk = base;
    #pragma unroll
    for (int j = 0; j < 8; ++j)
        if (m[j] == 0) idx[(size_t)b * Sz + (kk++)] = tid*8 + j;
    __syncthreads();
    const int sl2 = ssl;
    const int pad = (sl2 + 63) & ~63;
    if (pad > sl2) {
        for (int pr = tid; pr < Hz * Dz; pr += 256) {
            f16* dst = vt + ((size_t)b * Hz * Dz + pr) * Sz;
            for (int j = sl2; j < pad; ++j) dst[j] = (f16)0.f;
        }
    }
}

// ===========================================================================
// cast: blocks 0..4095 -> q fp32->f16 one-shot (R6-measured shape).
// blocks 4096..12287 -> k/v rows GATHERED by idx and written COMPACTED
// (row rank j <- source row idx[b][j]); one wave per row (2KB read, 1KB
// write), rows >= slen exit. Cuts cast traffic 151 -> ~100 MB and lets
// proj stage k/v linearly.
// ===========================================================================
__global__ __launch_bounds__(256)
void cast_kernel(const float* __restrict__ q, const float* __restrict__ key,
                 const float* __restrict__ value, const int* __restrict__ idx,
                 const int* __restrict__ slen,
                 f16* __restrict__ qa, f16* __restrict__ ka, f16* __restrict__ va)
{
    const int blk = blockIdx.x;
    const int tid = threadIdx.x;
    if (blk < 4096) {
        const size_t off = ((size_t)blk * 256 + tid) * 8;
        float4 x0 = *(const float4*)&q[off];
        float4 x1 = *(const float4*)&q[off + 4];
        f16 h[8];
        f16x2 p0 = pkrtz(x0.x, x0.y), p1 = pkrtz(x0.z, x0.w);
        f16x2 p2 = pkrtz(x1.x, x1.y), p3 = pkrtz(x1.z, x1.w);
        h[0] = p0[0]; h[1] = p0[1]; h[2] = p1[0]; h[3] = p1[1];
        h[4] = p2[0]; h[5] = p2[1]; h[6] = p3[0]; h[7] = p3[1];
        *(uint4*)&qa[off] = *(uint4*)h;
        return;
    }
    const int r = blk - 4096;
    const int zt = r >> 12;                 // 0 = key, 1 = value
    const int rem = r & 4095;
    const int b = rem >> 9, grp = rem & 511;
    const int sl = slen[b];
    if (grp * 4 >= sl) return;
    const int w = tid >> 6, lane = tid & 63;
    const int j = grp * 4 + w;
    if (j >= sl) return;
    const int s = idx[(size_t)b * Sz + j];
    const float* srcp = ((zt == 0) ? key : value) + ((size_t)b * Sz + s) * Ez + lane * 8;
    f16* dst = ((zt == 0) ? ka : va) + ((size_t)b * Sz + j) * Ez + lane * 8;
    float4 x0 = *(const float4*)&srcp[0];
    float4 x1 = *(const float4*)&srcp[4];
    f16 h[8];
    f16x2 p0 = pkrtz(x0.x, x0.y), p1 = pkrtz(x0.z, x0.w);
    f16x2 p2 = pkrtz(x1.x, x1.y), p3 = pkrtz(x1.z, x1.w);
    h[0] = p0[0]; h[1] = p0[1]; h[2] = p1[0]; h[3] = p1[1];
    h[4] = p2[0]; h[5] = p2[1]; h[6] = p3[0]; h[7] = p3[1];
    *(uint4*)&dst[lane * 0] = *(uint4*)h;   // dst already offset by lane*8
}

// ===========================================================================
// proj_gemm: DOUBLE-buffered DMA staging, 128x128 tile, BK=32.
// z picks {q,k,v}; k/v activations are PRE-COMPACTED so staging is linear
// (identical to z==0). Blocks past slen early-exit. Epilogue:
//  z==0: Q rows -> qp (B,H,S,D);  z==1: K rows -> kp (rank rows < slen)
//  z==2: V staged TRANSPOSED in LDS (Tr2[d][m]) then uint4 rank-run
//        stores into vt (B,H,D,Sz), clipped at slen.
// Garbage rows >= slen (unwritten ka/va) are safe: K garbage is zeroed
// post-exp (select) in attn; V garbage is clipped by the store limit.
// ===========================================================================
__global__ __launch_bounds__(256, 4)
void proj_gemm(const f16* __restrict__ qa, const f16* __restrict__ ka,
               const f16* __restrict__ va,
               const f16* __restrict__ wtq, const f16* __restrict__ wtk,
               const f16* __restrict__ wtv,
               const float* __restrict__ bqp, const float* __restrict__ bkp,
               const float* __restrict__ bvp, const int* __restrict__ slen,
               f16* __restrict__ qp, f16* __restrict__ kp, f16* __restrict__ vt)
{
    __shared__ __align__(16) char lds[32768];
    const int z = blockIdx.z;
    const int m0 = blockIdx.x * 128, n0 = blockIdx.y * 128;
    const int bb = m0 >> 11;
    const int m0c = m0 & (Sz - 1);

    int sl = Sz;
    if (z != 0) {
        sl = slen[bb];
        if (m0c >= sl) return;      // uniform early-exit: tile fully past slen
    }

    const f16* A  = (z==0)?qa:(z==1)?ka:va;
    const f16* Wt = (z==0)?wtq:(z==1)?wtk:wtv;
    const float* bias = (z==0)?bqp:(z==1)?bkp:bvp;
    const float bscale = (z==0) ? 0.125f*LOG2E : 1.0f;

    const int tid  = threadIdx.x;
    const int lane = tid & 63, w = tid >> 6;
    const int col  = lane & 15, quad = lane >> 4;
    const int wm = w & 1, wn = w >> 1;
    const int srow = lane >> 2, schunk = lane & 3;

    f32x4 acc[4][4];
    #pragma unroll
    for (int i = 0; i < 4; ++i)
        #pragma unroll
        for (int j = 0; j < 4; ++j) acc[i][j] = (f32x4){0.f,0.f,0.f,0.f};

    auto issue = [&](int t, int buf) {
        f16* As = (f16*)(lds + buf * 16384);
        f16* Ws = As + 4096;
        #pragma unroll
        for (int i = 0; i < 2; ++i) {
            const int row = w*32 + i*16 + srow;
            const int cl = schunk ^ ((row >> 1) & 3);
            async16(&A[(size_t)(m0 + row) * Ez + t*32 + cl*8],  &As[row*32 + schunk*8]);
            async16(&Wt[(size_t)(n0 + row) * Ez + t*32 + cl*8], &Ws[row*32 + schunk*8]);
        }
    };

    issue(0, 0);
    const int xrc = (col >> 1) & 3;

    for (int t = 0; t < 16; ++t) {
        const int cur = t & 1;
        __syncthreads();
        if (t < 15) issue(t + 1, cur ^ 1);
        f16* As = (f16*)(lds + cur * 16384);
        f16* Ws = As + 4096;
        f16x8 af[4];
        #pragma unroll
        for (int mi = 0; mi < 4; ++mi)
            af[mi] = *(const f16x8*)&As[(wm*64 + mi*16 + col)*32 + ((quad ^ xrc)*8)];
        #pragma unroll
        for (int ni = 0; ni < 4; ++ni) {
            f16x8 wf = *(const f16x8*)&Ws[(wn*64 + ni*16 + col)*32 + ((quad ^ xrc)*8)];
            #pragma unroll
            for (int mi = 0; mi < 4; ++mi)
                acc[mi][ni] = __builtin_amdgcn_mfma_f32_16x16x32_f16(af[mi], wf, acc[mi][ni], 0,0,0);
        }
    }

    const int rw = tid >> 1, half = tid & 1;

    f16* Tr  = (f16*)lds;    // z<2:  [128][72] row-major (m, d)
    f16* Tr2 = (f16*)lds;    // z==2: [64][136] transposed (d, m)
    #pragma unroll
    for (int p = 0; p < 2; ++p) {
        __syncthreads();
        if (wn == p) {
            #pragma unroll
            for (int ni = 0; ni < 4; ++ni) {
                float bv = bias[n0 + p*64 + ni*16 + col] * bscale;
                #pragma unroll
                for (int mi = 0; mi < 4; ++mi)
                    #pragma unroll
                    for (int rr = 0; rr < 4; ++rr) {
                        const int ml = wm*64 + mi*16 + quad*4 + rr;
                        const float val = acc[mi][ni][rr] + bv;
                        if (z != 2) Tr[ml*72 + ni*16 + col] = (f16)val;
                        else        Tr2[(ni*16 + col)*136 + ml] = (f16)val;
                    }
            }
        }
        __syncthreads();
        const int hh = (n0 >> 6) + p;
        if (z != 2) {
            const int rank = m0c + rw;
            if (z == 0 || rank < sl) {
                f16* C16 = (z == 0) ? qp : kp;
                f16* dst = &C16[(((size_t)bb*Hz + hh)*Sz + rank)*Dz + half*32];
                const f16* srcp = &Tr[rw*72 + half*32];
                #pragma unroll
                for (int j = 0; j < 4; ++j)
                    *(uint4*)&dst[j*8] = *(const uint4*)&srcp[j*8];
            }
        } else {
            const int d = tid >> 2, mq = tid & 3;
            const int base = m0c + mq*32;
            if (base < sl) {
                f16* dstb = vt + (((size_t)bb*Hz + hh)*Dz + d)*Sz + base;
                const f16* srcr = &Tr2[d*136 + mq*32];
                int lim = sl - base; if (lim > 32) lim = 32;
                if (lim == 32) {
                    #pragma unroll
                    for (int g = 0; g < 4; ++g)
                        *(uint4*)&dstb[g*8] = *(const uint4*)&srcr[g*8];
                } else {
                    const int full = lim >> 3;
                    for (int g = 0; g < full; ++g)
                        *(uint4*)&dstb[g*8] = *(const uint4*)&srcr[g*8];
                    for (int e = full*8; e < lim; ++e) dstb[e] = srcr[e];
                }
            }
        }
    }
}

// ===========================================================================
// out_gemm: DOUBLE-buffered staging, 128x128 tile, fp32 row-major + bias.
// ===========================================================================
__global__ __launch_bounds__(256, 4)
void out_gemm(const f16* __restrict__ A, const f16* __restrict__ Wt,
              const float* __restrict__ bias, float* __restrict__ Cf)
{
    __shared__ __align__(16) char lds[32768];
    const int tid  = threadIdx.x;
    const int lane = tid & 63, w = tid >> 6;
    const int col  = lane & 15, quad = lane >> 4;
    const int wm = w & 1, wn = w >> 1;
    const int m0 = blockIdx.x * 128, n0 = blockIdx.y * 128;
    const int srow = lane >> 2, schunk = lane & 3;

    f32x4 acc[4][4];
    #pragma unroll
    for (int i = 0; i < 4; ++i)
        #pragma unroll
        for (int j = 0; j < 4; ++j) acc[i][j] = (f32x4){0.f,0.f,0.f,0.f};

    auto issue = [&](int t, int buf) {
        f16* As = (f16*)(lds + buf * 16384);
        f16* Ws = As + 4096;
        #pragma unroll
        for (int i = 0; i < 2; ++i) {
            int row = w*32 + i*16 + srow;
            int cl = schunk ^ ((row >> 1) & 3);
            async16(&A[(size_t)(m0 + row) * Ez + t*32 + cl*8],  &As[row*32 + schunk*8]);
            async16(&Wt[(size_t)(n0 + row) * Ez + t*32 + cl*8], &Ws[row*32 + schunk*8]);
        }
    };

    issue(0, 0);
    const int xrc = (col >> 1) & 3;

    for (int t = 0; t < 16; ++t) {
        const int cur = t & 1;
        __syncthreads();
        if (t < 15) issue(t + 1, cur ^ 1);
        f16* As = (f16*)(lds + cur * 16384);
        f16* Ws = As + 4096;
        f16x8 af[4];
        #pragma unroll
        for (int mi = 0; mi < 4; ++mi)
            af[mi] = *(const f16x8*)&As[(wm*64 + mi*16 + col)*32 + ((quad ^ xrc)*8)];
        #pragma unroll
        for (int ni = 0; ni < 4; ++ni) {
            f16x8 wf = *(const f16x8*)&Ws[(wn*64 + ni*16 + col)*32 + ((quad ^ xrc)*8)];
            #pragma unroll
            for (int mi = 0; mi < 4; ++mi)
                acc[mi][ni] = __builtin_amdgcn_mfma_f32_16x16x32_f16(af[mi], wf, acc[mi][ni], 0,0,0);
        }
    }

    #pragma unroll
    for (int ni = 0; ni < 4; ++ni) {
        int n = n0 + wn*64 + ni*16 + col;
        float bv = bias[n];
        #pragma unroll
        for (int mi = 0; mi < 4; ++mi)
            #pragma unroll
            for (int rr = 0; rr < 4; ++rr) {
                int m = m0 + wm*64 + mi*16 + quad*4 + rr;
                Cf[(size_t)m * Ez + n] = acc[mi][ni][rr] + bv;
            }
    }
}

// ===========================================================================
// Flash attention over compacted keys (R2 structure: double-buffer +
// __syncthreads drain; 32KB LDS, 4 blocks/CU). K pre-compacted; V
// pre-transposed and pad-zeroed, so tail P-zeroing keeps everything exact.
// ===========================================================================
__global__ __launch_bounds__(256, 4)
void attn_f16(const f16* __restrict__ Q, const f16* __restrict__ K,
              const f16* __restrict__ VT, const int* __restrict__ slen,
              f16* __restrict__ O)
{
    __shared__ __align__(16) f16 KS[2][64*64];
    __shared__ __align__(16) f16 VS[2][64*64];

    const int tid  = threadIdx.x;
    const int lane = tid & 63, w = tid >> 6;
    const int col  = lane & 15, quad = lane >> 4;

    const int blk = blockIdx.x;
    const int xcd = blk & 7, slot = blk >> 3;
    const int bh = xcd + 8 * (slot >> 4);
    const int qb = slot & 15;
    const int b = bh >> 3, h = bh & 7;

    const int sl = slen[b];
    int nt = (sl + 63) >> 6;
    if (nt < 1) nt = 1;

    const int q0 = qb * 128 + w * 32;

    f16x8 qf[2][2];
    #pragma unroll
    for (int qt = 0; qt < 2; ++qt)
        #pragma unroll
        for (int ks = 0; ks < 2; ++ks)
            qf[qt][ks] = *(const f16x8*)&Q[((size_t)bh*Sz + q0 + qt*16 + col)*Dz + ks*32 + quad*8];

    const f16* Kp = K + (size_t)bh * Sz * Dz;
    const f16* Vp = VT + (size_t)bh * Dz * Sz;

    const int srow = lane >> 3, sch = lane & 7;
    const int row0 = w*16 + srow, row1 = row0 + 8;
    const int cl0 = sch ^ swz(row0), cl1 = sch ^ swz(row1);

    int keyrow[4], gk[4];
    #pragma unroll
    for (int kc = 0; kc < 4; ++kc) {
        keyrow[kc] = 32*(kc>>1) + 8*(col>>2) + 4*(kc&1) + (col&3);
        gk[kc] = swz(keyrow[kc]);
    }

    f32x4 oacc[2][4];
    #pragma unroll
    for (int qt = 0; qt < 2; ++qt)
        #pragma unroll
        for (int dc = 0; dc < 4; ++dc) oacc[qt][dc] = (f32x4){0.f,0.f,0.f,0.f};
    const f32x4 zero4 = (f32x4){0.f, 0.f, 0.f, 0.f};
    f32x4 lacc[2] = {(f32x4){0.f,0.f,0.f,0.f}, (f32x4){0.f,0.f,0.f,0.f}};
    f16x8 one8;
    #pragma unroll
    for (int i = 0; i < 8; ++i) one8[i] = (f16)1.0f;

    auto issue = [&](int t, int buf) {
        async16(&Kp[(size_t)(t*64 + row0)*Dz + cl0*8], &KS[buf][row0*64 + sch*8]);
        async16(&Vp[(size_t)row0*Sz + t*64 + cl0*8],   &VS[buf][row0*64 + sch*8]);
        async16(&Kp[(size_t)(t*64 + row1)*Dz + cl1*8], &KS[buf][row1*64 + sch*8]);
        async16(&Vp[(size_t)row1*Sz + t*64 + cl1*8],   &VS[buf][row1*64 + sch*8]);
    };

    issue(0, 0);

    for (int t = 0; t < nt; ++t) {
        const int cur = t & 1;
        __syncthreads();
        if (t + 1 < nt) issue(t + 1, cur ^ 1);

        // ---- QK^T: S^T = K·Q^T (C initialized from persistent zero regs)
        f32x4 sc[2][4];
        __builtin_amdgcn_s_setprio(1);
        #pragma unroll
        for (int kc = 0; kc < 4; ++kc) {
            f16x8 kf0 = *(const f16x8*)&KS[cur][keyrow[kc]*64 + ((quad ^ gk[kc])*8)];
            f16x8 kf1 = *(const f16x8*)&KS[cur][keyrow[kc]*64 + (((4 + quad) ^ gk[kc])*8)];
            sc[0][kc] = __builtin_amdgcn_mfma_f32_16x16x32_f16(kf0, qf[0][0], zero4, 0,0,0);
            sc[1][kc] = __builtin_amdgcn_mfma_f32_16x16x32_f16(kf0, qf[1][0], zero4, 0,0,0);
            sc[0][kc] = __builtin_amdgcn_mfma_f32_16x16x32_f16(kf1, qf[0][1], sc[0][kc], 0,0,0);
            sc[1][kc] = __builtin_amdgcn_mfma_f32_16x16x32_f16(kf1, qf[1][1], sc[1][kc], 0,0,0);
        }
        __builtin_amdgcn_s_setprio(0);

        // ---- p = exp2(s) (raw v_exp_f32); zero tail on last tile (select is
        // NaN-proof for garbage K rows); pack B-frags
        const bool last = (t == nt - 1);
        union { f16x2 h2[4]; f16x8 h8; } ph[2][2];
        #pragma unroll
        for (int qt = 0; qt < 2; ++qt) {
            #pragma unroll
            for (int kg = 0; kg < 2; ++kg) {
                float e0 = __builtin_amdgcn_exp2f(sc[qt][2*kg][0]);
                float e1 = __builtin_amdgcn_exp2f(sc[qt][2*kg][1]);
                float e2 = __builtin_amdgcn_exp2f(sc[qt][2*kg][2]);
                float e3 = __builtin_amdgcn_exp2f(sc[qt][2*kg][3]);
                float e4 = __builtin_amdgcn_exp2f(sc[qt][2*kg+1][0]);
                float e5 = __builtin_amdgcn_exp2f(sc[qt][2*kg+1][1]);
                float e6 = __builtin_amdgcn_exp2f(sc[qt][2*kg+1][2]);
                float e7 = __builtin_amdgcn_exp2f(sc[qt][2*kg+1][3]);
                if (last) {
                    int rem = sl - t*64 - 32*kg - 8*quad;
                    e0 = (rem > 0) ? e0 : 0.f; e1 = (rem > 1) ? e1 : 0.f;
                    e2 = (rem > 2) ? e2 : 0.f; e3 = (rem > 3) ? e3 : 0.f;
                    e4 = (rem > 4) ? e4 : 0.f; e5 = (rem > 5) ? e5 : 0.f;
                    e6 = (rem > 6) ? e6 : 0.f; e7 = (rem > 7) ? e7 : 0.f;
                }
                ph[qt][kg].h2[0] = pkrtz(e0, e1);
                ph[qt][kg].h2[1] = pkrtz(e2, e3);
                ph[qt][kg].h2[2] = pkrtz(e4, e5);
                ph[qt][kg].h2[3] = pkrtz(e6, e7);
            }
        }

        // ---- lsum (ones-row MFMA) + PV: O^T += V^T·P^T
        __builtin_amdgcn_s_setprio(1);
        lacc[0] = __builtin_amdgcn_mfma_f32_16x16x32_f16(one8, ph[0][0].h8, lacc[0], 0,0,0);
        lacc[1] = __builtin_amdgcn_mfma_f32_16x16x32_f16(one8, ph[1][0].h8, lacc[1], 0,0,0);
        lacc[0] = __builtin_amdgcn_mfma_f32_16x16x32_f16(one8, ph[0][1].h8, lacc[0], 0,0,0);
        lacc[1] = __builtin_amdgcn_mfma_f32_16x16x32_f16(one8, ph[1][1].h8, lacc[1], 0,0,0);
        #pragma unroll
        for (int dc = 0; dc < 4; ++dc) {
            const int d = dc*16 + col;
            const int gd = swz(d);
            #pragma unroll
            for (int kg = 0; kg < 2; ++kg) {
                f16x8 vf = *(const f16x8*)&VS[cur][d*64 + (((kg*4 + quad) ^ gd)*8)];
                oacc[0][dc] = __builtin_amdgcn_mfma_f32_16x16x32_f16(vf, ph[0][kg].h8, oacc[0][dc], 0,0,0);
                oacc[1][dc] = __builtin_amdgcn_mfma_f32_16x16x32_f16(vf, ph[1][kg].h8, oacc[1][dc], 0,0,0);
            }
        }
        __builtin_amdgcn_s_setprio(0);
    }

    // lacc rows are identical (A = ones) -> no cross-lane reduce needed;
    // col = lane&15 matches oacc's query mapping.
    float inv[2];
    inv[0] = 1.0f / lacc[0][0];
    inv[1] = 1.0f / lacc[1][0];
    #pragma unroll
    for (int qt = 0; qt < 2; ++qt) {
        const int q = q0 + qt*16 + col;
        f16* op = &O[((size_t)b*Sz + q)*Ez + h*Dz];
        #pragma unroll
        for (int dc = 0; dc < 4; ++dc) {
            f16 ov[4] = {(f16)(oacc[qt][dc][0]*inv[qt]), (f16)(oacc[qt][dc][1]*inv[qt]),
                         (f16)(oacc[qt][dc][2]*inv[qt]), (f16)(oacc[qt][dc][3]*inv[qt])};
            *(uint2*)&op[dc*16 + quad*4] = *(uint2*)ov;
        }
    }
}

// ===========================================================================
extern "C" void kernel_launch(void* const* d_in, const int* in_sizes, int n_in,
                              void* d_out, int out_size, void* d_ws, size_t ws_size,
                              hipStream_t stream)
{
    const float* value = (const float*)d_in[0];
    const float* key   = (const float*)d_in[1];
    const float* query = (const float*)d_in[2];
    const int*   mask  = (const int*)d_in[3];
    const float* wq = (const float*)d_in[4];
    const float* bq = (const float*)d_in[5];
    const float* wk = (const float*)d_in[6];
    const float* bk = (const float*)d_in[7];
    const float* wv = (const float*)d_in[8];
    const float* bv = (const float*)d_in[9];
    const float* wo = (const float*)d_in[10];
    const float* bo = (const float*)d_in[11];
    float* out = (float*)d_out;

    const size_t nW   = (size_t)Ez * Ez;             // 262144
    const size_t nAct = (size_t)Bz * Sz * Ez;        // 8388608
    f16* wtq = (f16*)d_ws;
    f16* wtk = wtq + nW;
    f16* wtv = wtk + nW;
    f16* wto = wtv + nW;
    f16* qa  = wto + nW;
    f16* ka  = qa + nAct;
    f16* va  = ka + nAct;
    f16* qp  = va + nAct;
    f16* kp  = qp + nAct;
    f16* vt  = kp + nAct;
    f16* o16 = vt + nAct;
    int* idxp = (int*)(o16 + nAct);
    int* slenp = idxp + Bz * Sz;

    prep_kernel<<<264, 256, 0, stream>>>(wq, wk, wv, wo, wtq, wtk, wtv, wto,
                                         mask, idxp, slenp, vt);

    cast_kernel<<<12288, 256, 0, stream>>>(query, key, value, idxp, slenp,
                                           qa, ka, va);

    proj_gemm<<<dim3(128, 4, 3), 256, 0, stream>>>(qa, ka, va, wtq, wtk, wtv,
                                                   bq, bk, bv, slenp,
                                                   qp, kp, vt);

    attn_f16<<<1024, 256, 0, stream>>>(qp, kp, vt, slenp, o16);

    out_gemm<<<dim3(128, 4), 256, 0, stream>>>(o16, wto, bo, out);
}

// Round 10
// 274.428 us; speedup vs baseline: 1.0174x; 1.0045x over previous
//
#include <hip/hip_runtime.h>

#define Bz 8
#define Sz 2048
#define Ez 512
#define Hz 8
#define Dz 64

typedef _Float16 f16;
typedef __attribute__((ext_vector_type(2))) _Float16 f16x2;
typedef __attribute__((ext_vector_type(8))) _Float16 f16x8;
typedef __attribute__((ext_vector_type(4))) float f32x4;

#define LOG2E 1.44269504f

__device__ __forceinline__ void async16(const void* g, void* l) {
    __builtin_amdgcn_global_load_lds(
        (const __attribute__((address_space(1))) unsigned int*)g,
        (__attribute__((address_space(3))) unsigned int*)l, 16, 0, 0);
}

__device__ __forceinline__ f16x2 pkrtz(float a, float b) {
    return __builtin_bit_cast(f16x2, __builtin_amdgcn_cvt_pkrtz(a, b));
}

__device__ __forceinline__ int swz(int row) {
    return (row & 7) ^ ((2 * ((row >> 3) & 3)) & 7);
}

// ===========================================================================
// prep: blocks 0..255 -> weight transpose (W fp32 [k][n] -> Wt f16 [n][k],
// wq scaled by 0.125*log2e). blocks 256..263 -> mask scan: idx[b][j] = j-th
// unmasked key position, slen[b] = count; zero-fills vt rank-pad
// [slen, ceil64(slen)) so attn's PV never multiplies NaN garbage.
// ===========================================================================
__global__ __launch_bounds__(256)
void prep_kernel(const float* __restrict__ W0, const float* __restrict__ W1,
                 const float* __restrict__ W2, const float* __restrict__ W3,
                 f16* __restrict__ T0, f16* __restrict__ T1,
                 f16* __restrict__ T2, f16* __restrict__ T3,
                 const int* __restrict__ mask, int* __restrict__ idx,
                 int* __restrict__ slen, f16* __restrict__ vt)
{
    const int blk = blockIdx.x;
    const int tid = threadIdx.x;
    if (blk < 256) {
        __shared__ float S[64][68];
        const int z = blk >> 6, rest = blk & 63;
        const float* W = (z==0)?W0:(z==1)?W1:(z==2)?W2:W3;
        f16*         T = (z==0)?T0:(z==1)?T1:(z==2)?T2:T3;
        const float sc = (z == 0) ? 0.125f * LOG2E : 1.0f;
        const int k0 = (rest & 7) * 64, n0 = (rest >> 3) * 64;
        {
            int kr = tid >> 4, nc = (tid & 15) * 4;
            #pragma unroll
            for (int i = 0; i < 4; ++i) {
                float4 w4 = *(const float4*)&W[(size_t)(k0 + kr + i*16) * Ez + n0 + nc];
                S[kr + i*16][nc+0] = w4.x; S[kr + i*16][nc+1] = w4.y;
                S[kr + i*16][nc+2] = w4.z; S[kr + i*16][nc+3] = w4.w;
            }
        }
        __syncthreads();
        {
            int n = tid >> 2, kq = tid & 3;
            f16 h[16];
            #pragma unroll
            for (int j = 0; j < 16; ++j) h[j] = (f16)(S[kq*16 + j][n] * sc);
            f16* dst = &T[(size_t)(n0 + n) * Ez + k0 + kq*16];
            *(uint4*)&dst[0] = *(uint4*)&h[0];
            *(uint4*)&dst[8] = *(uint4*)&h[8];
        }
        return;
    }
    const int b = blk - 256;
    if (b >= Bz) return;
    __shared__ int sc2[2][256];
    __shared__ int ssl;
    const int* mp = mask + (size_t)b * Sz;
    int m[8], c = 0;
    #pragma unroll
    for (int j = 0; j < 8; ++j) { m[j] = mp[tid*8 + j]; c += (m[j] == 0); }
    sc2[0][tid] = c;
    __syncthreads();
    int src = 0;
    #pragma unroll
    for (int s = 1; s < 256; s <<= 1) {
        int vv = sc2[src][tid] + ((tid >= s) ? sc2[src][tid - s] : 0);
        sc2[src ^ 1][tid] = vv;
        src ^= 1;
        __syncthreads();
    }
    int incl = sc2[src][tid];
    int base = incl - c;
    if (tid == 255) { slen[b] = incl; ssl = incl; }
    int kk = base;
    #pragma unroll
    for (int j = 0; j < 8; ++j)
        if (m[j] == 0) idx[(size_t)b * Sz + (kk++)] = tid*8 + j;
    __syncthreads();
    const int sl2 = ssl;
    const int pad = (sl2 + 63) & ~63;
    if (pad > sl2) {
        for (int pr = tid; pr < Hz * Dz; pr += 256) {
            f16* dst = vt + ((size_t)b * Hz * Dz + pr) * Sz;
            for (int j = sl2; j < pad; ++j) dst[j] = (f16)0.f;
        }
    }
}

// ===========================================================================
// proj_gemm: 128x128 tile, BK=32, double-buffered. CAST IS FUSED: the
// A-operand is the fp32 activation, loaded to REGISTERS, converted with
// cvt_pkrtz, ds_write'd into LDS with the SAME XOR chunk-swizzle as the
// DMA path (store chunk schunk at position schunk^((srow>>1)&3); read at
// quad^((col>>1)&3)) -- conflict-free on both sides. W stays on the f16
// DMA path. z==0: A = query (rows linear); z==1/2: A = key/value rows
// GATHERED by idx (per-thread row base). Blocks past slen early-exit.
// Epilogue: z==0 -> qp; z==1 -> kp (rank rows < slen); z==2 -> V staged
// transposed (Tr2[d][m]) then uint4 rank-run stores into vt, clipped.
// Garbage rows >= slen: K zeroed post-exp (select, NaN-proof) in attn;
// V clipped by the store limit; vt pad pre-zeroed by prep.
// ===========================================================================
__global__ __launch_bounds__(256, 4)
void proj_gemm(const float* __restrict__ Aq, const float* __restrict__ Ak,
               const float* __restrict__ Av,
               const f16* __restrict__ wtq, const f16* __restrict__ wtk,
               const f16* __restrict__ wtv,
               const float* __restrict__ bqp, const float* __restrict__ bkp,
               const float* __restrict__ bvp, const int* __restrict__ idx,
               const int* __restrict__ slen,
               f16* __restrict__ qp, f16* __restrict__ kp, f16* __restrict__ vt)
{
    __shared__ __align__(16) char lds[32768];
    const int z = blockIdx.z;
    const int m0 = blockIdx.x * 128, n0 = blockIdx.y * 128;
    const int bb = m0 >> 11;
    const int m0c = m0 & (Sz - 1);

    int sl = Sz;
    if (z != 0) {
        sl = slen[bb];
        if (m0c >= sl) return;      // uniform early-exit: tile fully past slen
    }

    const float* Af = (z==0)?Aq:(z==1)?Ak:Av;
    const f16* Wt = (z==0)?wtq:(z==1)?wtk:wtv;
    const float* bias = (z==0)?bqp:(z==1)?bkp:bvp;
    const float bscale = (z==0) ? 0.125f*LOG2E : 1.0f;

    const int tid  = threadIdx.x;
    const int lane = tid & 63, w = tid >> 6;
    const int col  = lane & 15, quad = lane >> 4;
    const int wm = w & 1, wn = w >> 1;
    const int srow = lane >> 2, schunk = lane & 3;
    const int awp = schunk ^ ((srow >> 1) & 3);   // swizzled A write position

    // per-thread fp32 A-row bases (rank-gathered for K/V)
    size_t arow[2];
    #pragma unroll
    for (int i = 0; i < 2; ++i) {
        const int row = w*32 + i*16 + srow;
        if (z == 0) {
            arow[i] = (size_t)(m0 + row) * Ez;
        } else {
            const int j = m0c + row;
            const int jc = (j < sl) ? j : sl - 1;
            arow[i] = ((size_t)bb * Sz + idx[(size_t)bb * Sz + jc]) * Ez;
        }
    }

    f32x4 acc[4][4];
    #pragma unroll
    for (int i = 0; i < 4; ++i)
        #pragma unroll
        for (int j = 0; j < 4; ++j) acc[i][j] = (f32x4){0.f,0.f,0.f,0.f};

    float4 ar[2][2];
    auto loadA = [&](int t) {
        #pragma unroll
        for (int i = 0; i < 2; ++i) {
            const float* p = &Af[arow[i] + t*32 + schunk*8];
            ar[i][0] = *(const float4*)&p[0];
            ar[i][1] = *(const float4*)&p[4];
        }
    };
    auto writeA = [&](int buf) {
        f16* As = (f16*)(lds + buf * 16384);
        #pragma unroll
        for (int i = 0; i < 2; ++i) {
            f16 h[8];
            f16x2 p0 = pkrtz(ar[i][0].x, ar[i][0].y), p1 = pkrtz(ar[i][0].z, ar[i][0].w);
            f16x2 p2 = pkrtz(ar[i][1].x, ar[i][1].y), p3 = pkrtz(ar[i][1].z, ar[i][1].w);
            h[0] = p0[0]; h[1] = p0[1]; h[2] = p1[0]; h[3] = p1[1];
            h[4] = p2[0]; h[5] = p2[1]; h[6] = p3[0]; h[7] = p3[1];
            // data chunk schunk stored at swizzled position awp
            *(uint4*)&As[(w*32 + i*16 + srow)*32 + awp*8] = *(uint4*)h;
        }
    };
    auto issueW = [&](int t, int buf) {
        f16* Ws = (f16*)(lds + buf * 16384) + 4096;
        #pragma unroll
        for (int i = 0; i < 2; ++i) {
            const int row = w*32 + i*16 + srow;
            const int cl = schunk ^ ((row >> 1) & 3);
            async16(&Wt[(size_t)(n0 + row) * Ez + t*32 + cl*8], &Ws[row*32 + schunk*8]);
        }
    };

    loadA(0);
    issueW(0, 0);
    writeA(0);
    const int xrc = (col >> 1) & 3;

    for (int t = 0; t < 16; ++t) {
        const int cur = t & 1;
        __syncthreads();
        if (t < 15) { issueW(t + 1, cur ^ 1); loadA(t + 1); }
        f16* As = (f16*)(lds + cur * 16384);
        f16* Ws = As + 4096;
        f16x8 af[4];
        #pragma unroll
        for (int mi = 0; mi < 4; ++mi)
            af[mi] = *(const f16x8*)&As[(wm*64 + mi*16 + col)*32 + ((quad ^ xrc)*8)];
        #pragma unroll
        for (int ni = 0; ni < 4; ++ni) {
            f16x8 wf = *(const f16x8*)&Ws[(wn*64 + ni*16 + col)*32 + ((quad ^ xrc)*8)];
            #pragma unroll
            for (int mi = 0; mi < 4; ++mi)
                acc[mi][ni] = __builtin_amdgcn_mfma_f32_16x16x32_f16(af[mi], wf, acc[mi][ni], 0,0,0);
        }
        if (t < 15) writeA(cur ^ 1);
    }

    const int rw = tid >> 1, half = tid & 1;

    f16* Tr  = (f16*)lds;    // z<2:  [128][72] row-major (m, d)
    f16* Tr2 = (f16*)lds;    // z==2: [64][136] transposed (d, m)
    #pragma unroll
    for (int p = 0; p < 2; ++p) {
        __syncthreads();
        if (wn == p) {
            #pragma unroll
            for (int ni = 0; ni < 4; ++ni) {
                float bv = bias[n0 + p*64 + ni*16 + col] * bscale;
                #pragma unroll
                for (int mi = 0; mi < 4; ++mi)
                    #pragma unroll
                    for (int rr = 0; rr < 4; ++rr) {
                        const int ml = wm*64 + mi*16 + quad*4 + rr;
                        const float val = acc[mi][ni][rr] + bv;
                        if (z != 2) Tr[ml*72 + ni*16 + col] = (f16)val;
                        else        Tr2[(ni*16 + col)*136 + ml] = (f16)val;
                    }
            }
        }
        __syncthreads();
        const int hh = (n0 >> 6) + p;
        if (z != 2) {
            const int rank = m0c + rw;
            if (z == 0 || rank < sl) {
                f16* C16 = (z == 0) ? qp : kp;
                f16* dst = &C16[(((size_t)bb*Hz + hh)*Sz + rank)*Dz + half*32];
                const f16* srcp = &Tr[rw*72 + half*32];
                #pragma unroll
                for (int j = 0; j < 4; ++j)
                    *(uint4*)&dst[j*8] = *(const uint4*)&srcp[j*8];
            }
        } else {
            const int d = tid >> 2, mq = tid & 3;
            const int base = m0c + mq*32;
            if (base < sl) {
                f16* dstb = vt + (((size_t)bb*Hz + hh)*Dz + d)*Sz + base;
                const f16* srcr = &Tr2[d*136 + mq*32];
                int lim = sl - base; if (lim > 32) lim = 32;
                if (lim == 32) {
                    #pragma unroll
                    for (int g = 0; g < 4; ++g)
                        *(uint4*)&dstb[g*8] = *(const uint4*)&srcr[g*8];
                } else {
                    const int full = lim >> 3;
                    for (int g = 0; g < full; ++g)
                        *(uint4*)&dstb[g*8] = *(const uint4*)&srcr[g*8];
                    for (int e = full*8; e < lim; ++e) dstb[e] = srcr[e];
                }
            }
        }
    }
}

// ===========================================================================
// out_gemm: DOUBLE-buffered staging, 128x128 tile, fp32 row-major + bias.
// ===========================================================================
__global__ __launch_bounds__(256, 4)
void out_gemm(const f16* __restrict__ A, const f16* __restrict__ Wt,
              const float* __restrict__ bias, float* __restrict__ Cf)
{
    __shared__ __align__(16) char lds[32768];
    const int tid  = threadIdx.x;
    const int lane = tid & 63, w = tid >> 6;
    const int col  = lane & 15, quad = lane >> 4;
    const int wm = w & 1, wn = w >> 1;
    const int m0 = blockIdx.x * 128, n0 = blockIdx.y * 128;
    const int srow = lane >> 2, schunk = lane & 3;

    f32x4 acc[4][4];
    #pragma unroll
    for (int i = 0; i < 4; ++i)
        #pragma unroll
        for (int j = 0; j < 4; ++j) acc[i][j] = (f32x4){0.f,0.f,0.f,0.f};

    auto issue = [&](int t, int buf) {
        f16* As = (f16*)(lds + buf * 16384);
        f16* Ws = As + 4096;
        #pragma unroll
        for (int i = 0; i < 2; ++i) {
            int row = w*32 + i*16 + srow;
            int cl = schunk ^ ((row >> 1) & 3);
            async16(&A[(size_t)(m0 + row) * Ez + t*32 + cl*8],  &As[row*32 + schunk*8]);
            async16(&Wt[(size_t)(n0 + row) * Ez + t*32 + cl*8], &Ws[row*32 + schunk*8]);
        }
    };

    issue(0, 0);
    const int xrc = (col >> 1) & 3;

    for (int t = 0; t < 16; ++t) {
        const int cur = t & 1;
        __syncthreads();
        if (t < 15) issue(t + 1, cur ^ 1);
        f16* As = (f16*)(lds + cur * 16384);
        f16* Ws = As + 4096;
        f16x8 af[4];
        #pragma unroll
        for (int mi = 0; mi < 4; ++mi)
            af[mi] = *(const f16x8*)&As[(wm*64 + mi*16 + col)*32 + ((quad ^ xrc)*8)];
        #pragma unroll
        for (int ni = 0; ni < 4; ++ni) {
            f16x8 wf = *(const f16x8*)&Ws[(wn*64 + ni*16 + col)*32 + ((quad ^ xrc)*8)];
            #pragma unroll
            for (int mi = 0; mi < 4; ++mi)
                acc[mi][ni] = __builtin_amdgcn_mfma_f32_16x16x32_f16(af[mi], wf, acc[mi][ni], 0,0,0);
        }
    }

    #pragma unroll
    for (int ni = 0; ni < 4; ++ni) {
        int n = n0 + wn*64 + ni*16 + col;
        float bv = bias[n];
        #pragma unroll
        for (int mi = 0; mi < 4; ++mi)
            #pragma unroll
            for (int rr = 0; rr < 4; ++rr) {
                int m = m0 + wm*64 + mi*16 + quad*4 + rr;
                Cf[(size_t)m * Ez + n] = acc[mi][ni][rr] + bv;
            }
    }
}

// ===========================================================================
// Flash attention over compacted keys (R2 structure: double-buffer +
// __syncthreads drain; 32KB LDS, 4 blocks/CU). K pre-compacted; V
// pre-transposed and pad-zeroed, so tail P-zeroing keeps everything exact.
// ===========================================================================
__global__ __launch_bounds__(256, 4)
void attn_f16(const f16* __restrict__ Q, const f16* __restrict__ K,
              const f16* __restrict__ VT, const int* __restrict__ slen,
              f16* __restrict__ O)
{
    __shared__ __align__(16) f16 KS[2][64*64];
    __shared__ __align__(16) f16 VS[2][64*64];

    const int tid  = threadIdx.x;
    const int lane = tid & 63, w = tid >> 6;
    const int col  = lane & 15, quad = lane >> 4;

    const int blk = blockIdx.x;
    const int xcd = blk & 7, slot = blk >> 3;
    const int bh = xcd + 8 * (slot >> 4);
    const int qb = slot & 15;
    const int b = bh >> 3, h = bh & 7;

    const int sl = slen[b];
    int nt = (sl + 63) >> 6;
    if (nt < 1) nt = 1;

    const int q0 = qb * 128 + w * 32;

    f16x8 qf[2][2];
    #pragma unroll
    for (int qt = 0; qt < 2; ++qt)
        #pragma unroll
        for (int ks = 0; ks < 2; ++ks)
            qf[qt][ks] = *(const f16x8*)&Q[((size_t)bh*Sz + q0 + qt*16 + col)*Dz + ks*32 + quad*8];

    const f16* Kp = K + (size_t)bh * Sz * Dz;
    const f16* Vp = VT + (size_t)bh * Dz * Sz;

    const int srow = lane >> 3, sch = lane & 7;
    const int row0 = w*16 + srow, row1 = row0 + 8;
    const int cl0 = sch ^ swz(row0), cl1 = sch ^ swz(row1);

    int keyrow[4], gk[4];
    #pragma unroll
    for (int kc = 0; kc < 4; ++kc) {
        keyrow[kc] = 32*(kc>>1) + 8*(col>>2) + 4*(kc&1) + (col&3);
        gk[kc] = swz(keyrow[kc]);
    }

    f32x4 oacc[2][4];
    #pragma unroll
    for (int qt = 0; qt < 2; ++qt)
        #pragma unroll
        for (int dc = 0; dc < 4; ++dc) oacc[qt][dc] = (f32x4){0.f,0.f,0.f,0.f};
    const f32x4 zero4 = (f32x4){0.f, 0.f, 0.f, 0.f};
    f32x4 lacc[2] = {(f32x4){0.f,0.f,0.f,0.f}, (f32x4){0.f,0.f,0.f,0.f}};
    f16x8 one8;
    #pragma unroll
    for (int i = 0; i < 8; ++i) one8[i] = (f16)1.0f;

    auto issue = [&](int t, int buf) {
        async16(&Kp[(size_t)(t*64 + row0)*Dz + cl0*8], &KS[buf][row0*64 + sch*8]);
        async16(&Vp[(size_t)row0*Sz + t*64 + cl0*8],   &VS[buf][row0*64 + sch*8]);
        async16(&Kp[(size_t)(t*64 + row1)*Dz + cl1*8], &KS[buf][row1*64 + sch*8]);
        async16(&Vp[(size_t)row1*Sz + t*64 + cl1*8],   &VS[buf][row1*64 + sch*8]);
    };

    issue(0, 0);

    for (int t = 0; t < nt; ++t) {
        const int cur = t & 1;
        __syncthreads();
        if (t + 1 < nt) issue(t + 1, cur ^ 1);

        // ---- QK^T: S^T = K·Q^T (C initialized from persistent zero regs)
        f32x4 sc[2][4];
        __builtin_amdgcn_s_setprio(1);
        #pragma unroll
        for (int kc = 0; kc < 4; ++kc) {
            f16x8 kf0 = *(const f16x8*)&KS[cur][keyrow[kc]*64 + ((quad ^ gk[kc])*8)];
            f16x8 kf1 = *(const f16x8*)&KS[cur][keyrow[kc]*64 + (((4 + quad) ^ gk[kc])*8)];
            sc[0][kc] = __builtin_amdgcn_mfma_f32_16x16x32_f16(kf0, qf[0][0], zero4, 0,0,0);
            sc[1][kc] = __builtin_amdgcn_mfma_f32_16x16x32_f16(kf0, qf[1][0], zero4, 0,0,0);
            sc[0][kc] = __builtin_amdgcn_mfma_f32_16x16x32_f16(kf1, qf[0][1], sc[0][kc], 0,0,0);
            sc[1][kc] = __builtin_amdgcn_mfma_f32_16x16x32_f16(kf1, qf[1][1], sc[1][kc], 0,0,0);
        }
        __builtin_amdgcn_s_setprio(0);

        // ---- p = exp2(s) (raw v_exp_f32); zero tail on last tile (select is
        // NaN-proof for garbage K rows); pack B-frags
        const bool last = (t == nt - 1);
        union { f16x2 h2[4]; f16x8 h8; } ph[2][2];
        #pragma unroll
        for (int qt = 0; qt < 2; ++qt) {
            #pragma unroll
            for (int kg = 0; kg < 2; ++kg) {
                float e0 = __builtin_amdgcn_exp2f(sc[qt][2*kg][0]);
                float e1 = __builtin_amdgcn_exp2f(sc[qt][2*kg][1]);
                float e2 = __builtin_amdgcn_exp2f(sc[qt][2*kg][2]);
                float e3 = __builtin_amdgcn_exp2f(sc[qt][2*kg][3]);
                float e4 = __builtin_amdgcn_exp2f(sc[qt][2*kg+1][0]);
                float e5 = __builtin_amdgcn_exp2f(sc[qt][2*kg+1][1]);
                float e6 = __builtin_amdgcn_exp2f(sc[qt][2*kg+1][2]);
                float e7 = __builtin_amdgcn_exp2f(sc[qt][2*kg+1][3]);
                if (last) {
                    int rem = sl - t*64 - 32*kg - 8*quad;
                    e0 = (rem > 0) ? e0 : 0.f; e1 = (rem > 1) ? e1 : 0.f;
                    e2 = (rem > 2) ? e2 : 0.f; e3 = (rem > 3) ? e3 : 0.f;
                    e4 = (rem > 4) ? e4 : 0.f; e5 = (rem > 5) ? e5 : 0.f;
                    e6 = (rem > 6) ? e6 : 0.f; e7 = (rem > 7) ? e7 : 0.f;
                }
                ph[qt][kg].h2[0] = pkrtz(e0, e1);
                ph[qt][kg].h2[1] = pkrtz(e2, e3);
                ph[qt][kg].h2[2] = pkrtz(e4, e5);
                ph[qt][kg].h2[3] = pkrtz(e6, e7);
            }
        }

        // ---- lsum (ones-row MFMA) + PV: O^T += V^T·P^T
        __builtin_amdgcn_s_setprio(1);
        lacc[0] = __builtin_amdgcn_mfma_f32_16x16x32_f16(one8, ph[0][0].h8, lacc[0], 0,0,0);
        lacc[1] = __builtin_amdgcn_mfma_f32_16x16x32_f16(one8, ph[1][0].h8, lacc[1], 0,0,0);
        lacc[0] = __builtin_amdgcn_mfma_f32_16x16x32_f16(one8, ph[0][1].h8, lacc[0], 0,0,0);
        lacc[1] = __builtin_amdgcn_mfma_f32_16x16x32_f16(one8, ph[1][1].h8, lacc[1], 0,0,0);
        #pragma unroll
        for (int dc = 0; dc < 4; ++dc) {
            const int d = dc*16 + col;
            const int gd = swz(d);
            #pragma unroll
            for (int kg = 0; kg < 2; ++kg) {
                f16x8 vf = *(const f16x8*)&VS[cur][d*64 + (((kg*4 + quad) ^ gd)*8)];
                oacc[0][dc] = __builtin_amdgcn_mfma_f32_16x16x32_f16(vf, ph[0][kg].h8, oacc[0][dc], 0,0,0);
                oacc[1][dc] = __builtin_amdgcn_mfma_f32_16x16x32_f16(vf, ph[1][kg].h8, oacc[1][dc], 0,0,0);
            }
        }
        __builtin_amdgcn_s_setprio(0);
    }

    // lacc rows are identical (A = ones) -> no cross-lane reduce needed;
    // col = lane&15 matches oacc's query mapping.
    float inv[2];
    inv[0] = 1.0f / lacc[0][0];
    inv[1] = 1.0f / lacc[1][0];
    #pragma unroll
    for (int qt = 0; qt < 2; ++qt) {
        const int q = q0 + qt*16 + col;
        f16* op = &O[((size_t)b*Sz + q)*Ez + h*Dz];
        #pragma unroll
        for (int dc = 0; dc < 4; ++dc) {
            f16 ov[4] = {(f16)(oacc[qt][dc][0]*inv[qt]), (f16)(oacc[qt][dc][1]*inv[qt]),
                         (f16)(oacc[qt][dc][2]*inv[qt]), (f16)(oacc[qt][dc][3]*inv[qt])};
            *(uint2*)&op[dc*16 + quad*4] = *(uint2*)ov;
        }
    }
}

// ===========================================================================
extern "C" void kernel_launch(void* const* d_in, const int* in_sizes, int n_in,
                              void* d_out, int out_size, void* d_ws, size_t ws_size,
                              hipStream_t stream)
{
    const float* value = (const float*)d_in[0];
    const float* key   = (const float*)d_in[1];
    const float* query = (const float*)d_in[2];
    const int*   mask  = (const int*)d_in[3];
    const float* wq = (const float*)d_in[4];
    const float* bq = (const float*)d_in[5];
    const float* wk = (const float*)d_in[6];
    const float* bk = (const float*)d_in[7];
    const float* wv = (const float*)d_in[8];
    const float* bv = (const float*)d_in[9];
    const float* wo = (const float*)d_in[10];
    const float* bo = (const float*)d_in[11];
    float* out = (float*)d_out;

    const size_t nW   = (size_t)Ez * Ez;             // 262144
    const size_t nAct = (size_t)Bz * Sz * Ez;        // 8388608
    f16* wtq = (f16*)d_ws;
    f16* wtk = wtq + nW;
    f16* wtv = wtk + nW;
    f16* wto = wtv + nW;
    f16* qp  = wto + nW;
    f16* kp  = qp + nAct;
    f16* vt  = kp + nAct;
    f16* o16 = vt + nAct;
    int* idxp = (int*)(o16 + nAct);
    int* slenp = idxp + Bz * Sz;

    prep_kernel<<<264, 256, 0, stream>>>(wq, wk, wv, wo, wtq, wtk, wtv, wto,
                                         mask, idxp, slenp, vt);

    proj_gemm<<<dim3(128, 4, 3), 256, 0, stream>>>(query, key, value,
                                                   wtq, wtk, wtv,
                                                   bq, bk, bv, idxp, slenp,
                                                   qp, kp, vt);

    attn_f16<<<1024, 256, 0, stream>>>(qp, kp, vt, slenp, o16);

    out_gemm<<<dim3(128, 4), 256, 0, stream>>>(o16, wto, bo, out);
}

// Round 11
// 272.709 us; speedup vs baseline: 1.0238x; 1.0063x over previous
//
#include <hip/hip_runtime.h>

#define Bz 8
#define Sz 2048
#define Ez 512
#define Hz 8
#define Dz 64

typedef _Float16 f16;
typedef __attribute__((ext_vector_type(2))) _Float16 f16x2;
typedef __attribute__((ext_vector_type(8))) _Float16 f16x8;
typedef __attribute__((ext_vector_type(4))) float f32x4;

#define LOG2E 1.44269504f

__device__ __forceinline__ void async16(const void* g, void* l) {
    __builtin_amdgcn_global_load_lds(
        (const __attribute__((address_space(1))) unsigned int*)g,
        (__attribute__((address_space(3))) unsigned int*)l, 16, 0, 0);
}

__device__ __forceinline__ f16x2 pkrtz(float a, float b) {
    return __builtin_bit_cast(f16x2, __builtin_amdgcn_cvt_pkrtz(a, b));
}

__device__ __forceinline__ int swz(int row) {
    return (row & 7) ^ ((2 * ((row >> 3) & 3)) & 7);
}

// ===========================================================================
// stage0: ONE launch for all independent preprocessing (launch-count lever).
//  blocks 0..24575      : fp32 -> f16 cast of q/k/v (one-shot, 4 elems/thread
//                         -- the R6-measured best shape for this op)
//  blocks 24576..24831  : weight transpose W[k][n] -> Wt[n][k], wq scaled
//  blocks 24832..24839  : mask scan (idx, slen) + vt rank-pad zero-fill
// ===========================================================================
__global__ __launch_bounds__(256)
void stage0(const float* __restrict__ q, const float* __restrict__ k,
            const float* __restrict__ v, const int* __restrict__ mask,
            const float* __restrict__ W0, const float* __restrict__ W1,
            const float* __restrict__ W2, const float* __restrict__ W3,
            f16* __restrict__ T0, f16* __restrict__ T1,
            f16* __restrict__ T2, f16* __restrict__ T3,
            f16* __restrict__ qa, f16* __restrict__ ka, f16* __restrict__ va,
            int* __restrict__ idx, int* __restrict__ slen, f16* __restrict__ vt)
{
    __shared__ __align__(16) char sh[64 * 68 * 4];
    const int blk = blockIdx.x;
    const int tid = threadIdx.x;

    if (blk < 24576) {
        const int z = blk >> 13;
        const size_t i = ((size_t)(blk & 8191) * 256 + tid) * 4;
        const float* src = (z == 0) ? q : (z == 1) ? k : v;
        f16* dst = (z == 0) ? qa : (z == 1) ? ka : va;
        float4 x = *(const float4*)&src[i];
        f16x2 h0 = pkrtz(x.x, x.y), h1 = pkrtz(x.z, x.w);
        f16 h[4] = {h0[0], h0[1], h1[0], h1[1]};
        *(uint2*)&dst[i] = *(uint2*)h;
        return;
    }

    if (blk < 24832) {
        float (*S)[68] = (float(*)[68])sh;
        const int rest = blk - 24576;
        const int z = rest >> 6, r2 = rest & 63;
        const float* W = (z==0)?W0:(z==1)?W1:(z==2)?W2:W3;
        f16*         T = (z==0)?T0:(z==1)?T1:(z==2)?T2:T3;
        const float sc = (z == 0) ? 0.125f * LOG2E : 1.0f;
        const int k0 = (r2 & 7) * 64, n0 = (r2 >> 3) * 64;
        {
            int kr = tid >> 4, nc = (tid & 15) * 4;
            #pragma unroll
            for (int i = 0; i < 4; ++i) {
                float4 w4 = *(const float4*)&W[(size_t)(k0 + kr + i*16) * Ez + n0 + nc];
                S[kr + i*16][nc+0] = w4.x; S[kr + i*16][nc+1] = w4.y;
                S[kr + i*16][nc+2] = w4.z; S[kr + i*16][nc+3] = w4.w;
            }
        }
        __syncthreads();
        {
            int n = tid >> 2, kq = tid & 3;
            f16 h[16];
            #pragma unroll
            for (int j = 0; j < 16; ++j) h[j] = (f16)(S[kq*16 + j][n] * sc);
            f16* dst = &T[(size_t)(n0 + n) * Ez + k0 + kq*16];
            *(uint4*)&dst[0] = *(uint4*)&h[0];
            *(uint4*)&dst[8] = *(uint4*)&h[8];
        }
        return;
    }

    const int b = blk - 24832;
    if (b >= Bz) return;
    int (*sc2)[256] = (int(*)[256])sh;
    __shared__ int ssl;
    const int* mp = mask + (size_t)b * Sz;
    int m[8], c = 0;
    #pragma unroll
    for (int j = 0; j < 8; ++j) { m[j] = mp[tid*8 + j]; c += (m[j] == 0); }
    sc2[0][tid] = c;
    __syncthreads();
    int src = 0;
    #pragma unroll
    for (int s = 1; s < 256; s <<= 1) {
        int vv = sc2[src][tid] + ((tid >= s) ? sc2[src][tid - s] : 0);
        sc2[src ^ 1][tid] = vv;
        src ^= 1;
        __syncthreads();
    }
    int incl = sc2[src][tid];
    int base = incl - c;
    if (tid == 255) { slen[b] = incl; ssl = incl; }
    int kk = base;
    #pragma unroll
    for (int j = 0; j < 8; ++j)
        if (m[j] == 0) idx[(size_t)b * Sz + (kk++)] = tid*8 + j;
    __syncthreads();
    const int sl2 = ssl;
    const int pad = (sl2 + 63) & ~63;
    if (pad > sl2) {
        for (int pr = tid; pr < Hz * Dz; pr += 256) {
            f16* dst = vt + ((size_t)b * Hz * Dz + pr) * Sz;
            for (int j = sl2; j < pad; ++j) dst[j] = (f16)0.f;
        }
    }
}

// ===========================================================================
// proj_gemm (R6 structure): DOUBLE-buffered DMA staging, 128x128 tile, BK=32.
// z picks {q,k,v}.
//  z==0: full M=16384; Q rows -> qp (B,H,S,D).
//  z==1/2: A rows GATHERED by rank via the per-lane global_load_lds SOURCE
//    address (LDS dest stays linear); M shrinks to slen[b], blocks past
//    slen early-exit. K rows -> kp dense-by-rank. V staged TRANSPOSED in
//    LDS (Tr2[d][m]) then uint4 rank-run stores into vt (B,H,D,Sz).
//  Tail ranks (>= slen) use clamped source rows; K garbage is zeroed
//  post-exp in attn (select, NaN-proof), V stores clipped at slen
//  (vt pad pre-zeroed by stage0).
// ===========================================================================
__global__ __launch_bounds__(256, 4)
void proj_gemm(const f16* __restrict__ qa, const f16* __restrict__ ka,
               const f16* __restrict__ va,
               const f16* __restrict__ wtq, const f16* __restrict__ wtk,
               const f16* __restrict__ wtv,
               const float* __restrict__ bqp, const float* __restrict__ bkp,
               const float* __restrict__ bvp, const int* __restrict__ idx,
               const int* __restrict__ slen,
               f16* __restrict__ qp, f16* __restrict__ kp, f16* __restrict__ vt)
{
    __shared__ __align__(16) char lds[32768];
    const int z = blockIdx.z;
    const int m0 = blockIdx.x * 128, n0 = blockIdx.y * 128;
    const int bb = m0 >> 11;
    const int m0c = m0 & (Sz - 1);

    int sl = Sz;
    if (z != 0) {
        sl = slen[bb];
        if (m0c >= sl) return;      // uniform early-exit: tile fully past slen
    }

    const f16* A  = (z==0)?qa:(z==1)?ka:va;
    const f16* Wt = (z==0)?wtq:(z==1)?wtk:wtv;
    const float* bias = (z==0)?bqp:(z==1)?bkp:bvp;
    const float bscale = (z==0) ? 0.125f*LOG2E : 1.0f;

    const int tid  = threadIdx.x;
    const int lane = tid & 63, w = tid >> 6;
    const int col  = lane & 15, quad = lane >> 4;
    const int wm = w & 1, wn = w >> 1;
    const int srow = lane >> 2, schunk = lane & 3;

    // per-thread staging source row bases (rank-gathered for K/V)
    size_t rb[2];
    int clv[2];
    #pragma unroll
    for (int i = 0; i < 2; ++i) {
        const int row = w*32 + i*16 + srow;
        clv[i] = schunk ^ ((row >> 1) & 3);
        const int j = m0c + row;
        int srcrow;
        if (z == 0) {
            srcrow = j;
        } else {
            const int jc = (j < sl) ? j : sl - 1;
            srcrow = idx[(size_t)bb * Sz + jc];
        }
        rb[i] = ((size_t)bb * Sz + srcrow) * Ez;
    }

    f32x4 acc[4][4];
    #pragma unroll
    for (int i = 0; i < 4; ++i)
        #pragma unroll
        for (int j = 0; j < 4; ++j) acc[i][j] = (f32x4){0.f,0.f,0.f,0.f};

    auto issue = [&](int t, int buf) {
        f16* As = (f16*)(lds + buf * 16384);
        f16* Ws = As + 4096;
        #pragma unroll
        for (int i = 0; i < 2; ++i) {
            const int row = w*32 + i*16 + srow;
            async16(&A[rb[i] + t*32 + clv[i]*8],                    &As[row*32 + schunk*8]);
            async16(&Wt[(size_t)(n0 + row) * Ez + t*32 + clv[i]*8], &Ws[row*32 + schunk*8]);
        }
    };

    issue(0, 0);
    const int xrc = (col >> 1) & 3;

    for (int t = 0; t < 16; ++t) {
        const int cur = t & 1;
        __syncthreads();
        if (t < 15) issue(t + 1, cur ^ 1);
        f16* As = (f16*)(lds + cur * 16384);
        f16* Ws = As + 4096;
        f16x8 af[4];
        #pragma unroll
        for (int mi = 0; mi < 4; ++mi)
            af[mi] = *(const f16x8*)&As[(wm*64 + mi*16 + col)*32 + ((quad ^ xrc)*8)];
        #pragma unroll
        for (int ni = 0; ni < 4; ++ni) {
            f16x8 wf = *(const f16x8*)&Ws[(wn*64 + ni*16 + col)*32 + ((quad ^ xrc)*8)];
            #pragma unroll
            for (int mi = 0; mi < 4; ++mi)
                acc[mi][ni] = __builtin_amdgcn_mfma_f32_16x16x32_f16(af[mi], wf, acc[mi][ni], 0,0,0);
        }
    }

    const int rw = tid >> 1, half = tid & 1;

    f16* Tr  = (f16*)lds;    // z<2:  [128][72] row-major (m, d)
    f16* Tr2 = (f16*)lds;    // z==2: [64][136] transposed (d, m)
    #pragma unroll
    for (int p = 0; p < 2; ++p) {
        __syncthreads();
        if (wn == p) {
            #pragma unroll
            for (int ni = 0; ni < 4; ++ni) {
                float bv = bias[n0 + p*64 + ni*16 + col] * bscale;
                #pragma unroll
                for (int mi = 0; mi < 4; ++mi)
                    #pragma unroll
                    for (int rr = 0; rr < 4; ++rr) {
                        const int ml = wm*64 + mi*16 + quad*4 + rr;
                        const float val = acc[mi][ni][rr] + bv;
                        if (z != 2) Tr[ml*72 + ni*16 + col] = (f16)val;
                        else        Tr2[(ni*16 + col)*136 + ml] = (f16)val;
                    }
            }
        }
        __syncthreads();
        const int hh = (n0 >> 6) + p;
        if (z != 2) {
            const int rank = m0c + rw;
            if (z == 0 || rank < sl) {
                f16* C16 = (z == 0) ? qp : kp;
                f16* dst = &C16[(((size_t)bb*Hz + hh)*Sz + rank)*Dz + half*32];
                const f16* srcp = &Tr[rw*72 + half*32];
                #pragma unroll
                for (int j = 0; j < 4; ++j)
                    *(uint4*)&dst[j*8] = *(const uint4*)&srcp[j*8];
            }
        } else {
            const int d = tid >> 2, mq = tid & 3;
            const int base = m0c + mq*32;
            if (base < sl) {
                f16* dstb = vt + (((size_t)bb*Hz + hh)*Dz + d)*Sz + base;
                const f16* srcr = &Tr2[d*136 + mq*32];
                int lim = sl - base; if (lim > 32) lim = 32;
                if (lim == 32) {
                    #pragma unroll
                    for (int g = 0; g < 4; ++g)
                        *(uint4*)&dstb[g*8] = *(const uint4*)&srcr[g*8];
                } else {
                    const int full = lim >> 3;
                    for (int g = 0; g < full; ++g)
                        *(uint4*)&dstb[g*8] = *(const uint4*)&srcr[g*8];
                    for (int e = full*8; e < lim; ++e) dstb[e] = srcr[e];
                }
            }
        }
    }
}

// ===========================================================================
// out_gemm: DOUBLE-buffered staging, 128x128 tile, fp32 row-major + bias.
// ===========================================================================
__global__ __launch_bounds__(256, 4)
void out_gemm(const f16* __restrict__ A, const f16* __restrict__ Wt,
              const float* __restrict__ bias, float* __restrict__ Cf)
{
    __shared__ __align__(16) char lds[32768];
    const int tid  = threadIdx.x;
    const int lane = tid & 63, w = tid >> 6;
    const int col  = lane & 15, quad = lane >> 4;
    const int wm = w & 1, wn = w >> 1;
    const int m0 = blockIdx.x * 128, n0 = blockIdx.y * 128;
    const int srow = lane >> 2, schunk = lane & 3;

    f32x4 acc[4][4];
    #pragma unroll
    for (int i = 0; i < 4; ++i)
        #pragma unroll
        for (int j = 0; j < 4; ++j) acc[i][j] = (f32x4){0.f,0.f,0.f,0.f};

    auto issue = [&](int t, int buf) {
        f16* As = (f16*)(lds + buf * 16384);
        f16* Ws = As + 4096;
        #pragma unroll
        for (int i = 0; i < 2; ++i) {
            int row = w*32 + i*16 + srow;
            int cl = schunk ^ ((row >> 1) & 3);
            async16(&A[(size_t)(m0 + row) * Ez + t*32 + cl*8],  &As[row*32 + schunk*8]);
            async16(&Wt[(size_t)(n0 + row) * Ez + t*32 + cl*8], &Ws[row*32 + schunk*8]);
        }
    };

    issue(0, 0);
    const int xrc = (col >> 1) & 3;

    for (int t = 0; t < 16; ++t) {
        const int cur = t & 1;
        __syncthreads();
        if (t < 15) issue(t + 1, cur ^ 1);
        f16* As = (f16*)(lds + cur * 16384);
        f16* Ws = As + 4096;
        f16x8 af[4];
        #pragma unroll
        for (int mi = 0; mi < 4; ++mi)
            af[mi] = *(const f16x8*)&As[(wm*64 + mi*16 + col)*32 + ((quad ^ xrc)*8)];
        #pragma unroll
        for (int ni = 0; ni < 4; ++ni) {
            f16x8 wf = *(const f16x8*)&Ws[(wn*64 + ni*16 + col)*32 + ((quad ^ xrc)*8)];
            #pragma unroll
            for (int mi = 0; mi < 4; ++mi)
                acc[mi][ni] = __builtin_amdgcn_mfma_f32_16x16x32_f16(af[mi], wf, acc[mi][ni], 0,0,0);
        }
    }

    #pragma unroll
    for (int ni = 0; ni < 4; ++ni) {
        int n = n0 + wn*64 + ni*16 + col;
        float bv = bias[n];
        #pragma unroll
        for (int mi = 0; mi < 4; ++mi)
            #pragma unroll
            for (int rr = 0; rr < 4; ++rr) {
                int m = m0 + wm*64 + mi*16 + quad*4 + rr;
                Cf[(size_t)m * Ez + n] = acc[mi][ni][rr] + bv;
            }
    }
}

// ===========================================================================
// Flash attention over compacted keys (R2 structure: double-buffer +
// __syncthreads drain; 32KB LDS, 4 blocks/CU). K pre-compacted; V
// pre-transposed and pad-zeroed, so tail P-zeroing keeps everything exact.
// ===========================================================================
__global__ __launch_bounds__(256, 4)
void attn_f16(const f16* __restrict__ Q, const f16* __restrict__ K,
              const f16* __restrict__ VT, const int* __restrict__ slen,
              f16* __restrict__ O)
{
    __shared__ __align__(16) f16 KS[2][64*64];
    __shared__ __align__(16) f16 VS[2][64*64];

    const int tid  = threadIdx.x;
    const int lane = tid & 63, w = tid >> 6;
    const int col  = lane & 15, quad = lane >> 4;

    const int blk = blockIdx.x;
    const int xcd = blk & 7, slot = blk >> 3;
    const int bh = xcd + 8 * (slot >> 4);
    const int qb = slot & 15;
    const int b = bh >> 3, h = bh & 7;

    const int sl = slen[b];
    int nt = (sl + 63) >> 6;
    if (nt < 1) nt = 1;

    const int q0 = qb * 128 + w * 32;

    f16x8 qf[2][2];
    #pragma unroll
    for (int qt = 0; qt < 2; ++qt)
        #pragma unroll
        for (int ks = 0; ks < 2; ++ks)
            qf[qt][ks] = *(const f16x8*)&Q[((size_t)bh*Sz + q0 + qt*16 + col)*Dz + ks*32 + quad*8];

    const f16* Kp = K + (size_t)bh * Sz * Dz;
    const f16* Vp = VT + (size_t)bh * Dz * Sz;

    const int srow = lane >> 3, sch = lane & 7;
    const int row0 = w*16 + srow, row1 = row0 + 8;
    const int cl0 = sch ^ swz(row0), cl1 = sch ^ swz(row1);

    int keyrow[4], gk[4];
    #pragma unroll
    for (int kc = 0; kc < 4; ++kc) {
        keyrow[kc] = 32*(kc>>1) + 8*(col>>2) + 4*(kc&1) + (col&3);
        gk[kc] = swz(keyrow[kc]);
    }

    f32x4 oacc[2][4];
    #pragma unroll
    for (int qt = 0; qt < 2; ++qt)
        #pragma unroll
        for (int dc = 0; dc < 4; ++dc) oacc[qt][dc] = (f32x4){0.f,0.f,0.f,0.f};
    const f32x4 zero4 = (f32x4){0.f, 0.f, 0.f, 0.f};
    f32x4 lacc[2] = {(f32x4){0.f,0.f,0.f,0.f}, (f32x4){0.f,0.f,0.f,0.f}};
    f16x8 one8;
    #pragma unroll
    for (int i = 0; i < 8; ++i) one8[i] = (f16)1.0f;

    auto issue = [&](int t, int buf) {
        async16(&Kp[(size_t)(t*64 + row0)*Dz + cl0*8], &KS[buf][row0*64 + sch*8]);
        async16(&Vp[(size_t)row0*Sz + t*64 + cl0*8],   &VS[buf][row0*64 + sch*8]);
        async16(&Kp[(size_t)(t*64 + row1)*Dz + cl1*8], &KS[buf][row1*64 + sch*8]);
        async16(&Vp[(size_t)row1*Sz + t*64 + cl1*8],   &VS[buf][row1*64 + sch*8]);
    };

    issue(0, 0);

    for (int t = 0; t < nt; ++t) {
        const int cur = t & 1;
        __syncthreads();
        if (t + 1 < nt) issue(t + 1, cur ^ 1);

        // ---- QK^T: S^T = K·Q^T (C initialized from persistent zero regs)
        f32x4 sc[2][4];
        __builtin_amdgcn_s_setprio(1);
        #pragma unroll
        for (int kc = 0; kc < 4; ++kc) {
            f16x8 kf0 = *(const f16x8*)&KS[cur][keyrow[kc]*64 + ((quad ^ gk[kc])*8)];
            f16x8 kf1 = *(const f16x8*)&KS[cur][keyrow[kc]*64 + (((4 + quad) ^ gk[kc])*8)];
            sc[0][kc] = __builtin_amdgcn_mfma_f32_16x16x32_f16(kf0, qf[0][0], zero4, 0,0,0);
            sc[1][kc] = __builtin_amdgcn_mfma_f32_16x16x32_f16(kf0, qf[1][0], zero4, 0,0,0);
            sc[0][kc] = __builtin_amdgcn_mfma_f32_16x16x32_f16(kf1, qf[0][1], sc[0][kc], 0,0,0);
            sc[1][kc] = __builtin_amdgcn_mfma_f32_16x16x32_f16(kf1, qf[1][1], sc[1][kc], 0,0,0);
        }
        __builtin_amdgcn_s_setprio(0);

        // ---- p = exp2(s) (raw v_exp_f32); zero tail on last tile (select is
        // NaN-proof for garbage K rows); pack B-frags
        const bool last = (t == nt - 1);
        union { f16x2 h2[4]; f16x8 h8; } ph[2][2];
        #pragma unroll
        for (int qt = 0; qt < 2; ++qt) {
            #pragma unroll
            for (int kg = 0; kg < 2; ++kg) {
                float e0 = __builtin_amdgcn_exp2f(sc[qt][2*kg][0]);
                float e1 = __builtin_amdgcn_exp2f(sc[qt][2*kg][1]);
                float e2 = __builtin_amdgcn_exp2f(sc[qt][2*kg][2]);
                float e3 = __builtin_amdgcn_exp2f(sc[qt][2*kg][3]);
                float e4 = __builtin_amdgcn_exp2f(sc[qt][2*kg+1][0]);
                float e5 = __builtin_amdgcn_exp2f(sc[qt][2*kg+1][1]);
                float e6 = __builtin_amdgcn_exp2f(sc[qt][2*kg+1][2]);
                float e7 = __builtin_amdgcn_exp2f(sc[qt][2*kg+1][3]);
                if (last) {
                    int rem = sl - t*64 - 32*kg - 8*quad;
                    e0 = (rem > 0) ? e0 : 0.f; e1 = (rem > 1) ? e1 : 0.f;
                    e2 = (rem > 2) ? e2 : 0.f; e3 = (rem > 3) ? e3 : 0.f;
                    e4 = (rem > 4) ? e4 : 0.f; e5 = (rem > 5) ? e5 : 0.f;
                    e6 = (rem > 6) ? e6 : 0.f; e7 = (rem > 7) ? e7 : 0.f;
                }
                ph[qt][kg].h2[0] = pkrtz(e0, e1);
                ph[qt][kg].h2[1] = pkrtz(e2, e3);
                ph[qt][kg].h2[2] = pkrtz(e4, e5);
                ph[qt][kg].h2[3] = pkrtz(e6, e7);
            }
        }

        // ---- lsum (ones-row MFMA) + PV: O^T += V^T·P^T
        __builtin_amdgcn_s_setprio(1);
        lacc[0] = __builtin_amdgcn_mfma_f32_16x16x32_f16(one8, ph[0][0].h8, lacc[0], 0,0,0);
        lacc[1] = __builtin_amdgcn_mfma_f32_16x16x32_f16(one8, ph[1][0].h8, lacc[1], 0,0,0);
        lacc[0] = __builtin_amdgcn_mfma_f32_16x16x32_f16(one8, ph[0][1].h8, lacc[0], 0,0,0);
        lacc[1] = __builtin_amdgcn_mfma_f32_16x16x32_f16(one8, ph[1][1].h8, lacc[1], 0,0,0);
        #pragma unroll
        for (int dc = 0; dc < 4; ++dc) {
            const int d = dc*16 + col;
            const int gd = swz(d);
            #pragma unroll
            for (int kg = 0; kg < 2; ++kg) {
                f16x8 vf = *(const f16x8*)&VS[cur][d*64 + (((kg*4 + quad) ^ gd)*8)];
                oacc[0][dc] = __builtin_amdgcn_mfma_f32_16x16x32_f16(vf, ph[0][kg].h8, oacc[0][dc], 0,0,0);
                oacc[1][dc] = __builtin_amdgcn_mfma_f32_16x16x32_f16(vf, ph[1][kg].h8, oacc[1][dc], 0,0,0);
            }
        }
        __builtin_amdgcn_s_setprio(0);
    }

    // lacc rows are identical (A = ones) -> no cross-lane reduce needed;
    // col = lane&15 matches oacc's query mapping.
    float inv[2];
    inv[0] = 1.0f / lacc[0][0];
    inv[1] = 1.0f / lacc[1][0];
    #pragma unroll
    for (int qt = 0; qt < 2; ++qt) {
        const int q = q0 + qt*16 + col;
        f16* op = &O[((size_t)b*Sz + q)*Ez + h*Dz];
        #pragma unroll
        for (int dc = 0; dc < 4; ++dc) {
            f16 ov[4] = {(f16)(oacc[qt][dc][0]*inv[qt]), (f16)(oacc[qt][dc][1]*inv[qt]),
                         (f16)(oacc[qt][dc][2]*inv[qt]), (f16)(oacc[qt][dc][3]*inv[qt])};
            *(uint2*)&op[dc*16 + quad*4] = *(uint2*)ov;
        }
    }
}

// ===========================================================================
extern "C" void kernel_launch(void* const* d_in, const int* in_sizes, int n_in,
                              void* d_out, int out_size, void* d_ws, size_t ws_size,
                              hipStream_t stream)
{
    const float* value = (const float*)d_in[0];
    const float* key   = (const float*)d_in[1];
    const float* query = (const float*)d_in[2];
    const int*   mask  = (const int*)d_in[3];
    const float* wq = (const float*)d_in[4];
    const float* bq = (const float*)d_in[5];
    const float* wk = (const float*)d_in[6];
    const float* bk = (const float*)d_in[7];
    const float* wv = (const float*)d_in[8];
    const float* bv = (const float*)d_in[9];
    const float* wo = (const float*)d_in[10];
    const float* bo = (const float*)d_in[11];
    float* out = (float*)d_out;

    const size_t nW   = (size_t)Ez * Ez;             // 262144
    const size_t nAct = (size_t)Bz * Sz * Ez;        // 8388608
    f16* wtq = (f16*)d_ws;
    f16* wtk = wtq + nW;
    f16* wtv = wtk + nW;
    f16* wto = wtv + nW;
    f16* qa  = wto + nW;
    f16* ka  = qa + nAct;
    f16* va  = ka + nAct;
    f16* qp  = va + nAct;
    f16* kp  = qp + nAct;
    f16* vt  = kp + nAct;
    f16* o16 = vt + nAct;
    int* idxp = (int*)(o16 + nAct);
    int* slenp = idxp + Bz * Sz;

    stage0<<<24840, 256, 0, stream>>>(query, key, value, mask,
                                      wq, wk, wv, wo, wtq, wtk, wtv, wto,
                                      qa, ka, va, idxp, slenp, vt);

    proj_gemm<<<dim3(128, 4, 3), 256, 0, stream>>>(qa, ka, va, wtq, wtk, wtv,
                                                   bq, bk, bv, idxp, slenp,
                                                   qp, kp, vt);

    attn_f16<<<1024, 256, 0, stream>>>(qp, kp, vt, slenp, o16);

    out_gemm<<<dim3(128, 4), 256, 0, stream>>>(o16, wto, bo, out);
}

// Round 12
// 268.849 us; speedup vs baseline: 1.0385x; 1.0144x over previous
//
#include <hip/hip_runtime.h>

#define Bz 8
#define Sz 2048
#define Ez 512
#define Hz 8
#define Dz 64

typedef _Float16 f16;
typedef __attribute__((ext_vector_type(2))) _Float16 f16x2;
typedef __attribute__((ext_vector_type(8))) _Float16 f16x8;
typedef __attribute__((ext_vector_type(4))) float f32x4;

#define LOG2E 1.44269504f

__device__ __forceinline__ void async16(const void* g, void* l) {
    __builtin_amdgcn_global_load_lds(
        (const __attribute__((address_space(1))) unsigned int*)g,
        (__attribute__((address_space(3))) unsigned int*)l, 16, 0, 0);
}

__device__ __forceinline__ f16x2 pkrtz(float a, float b) {
    return __builtin_bit_cast(f16x2, __builtin_amdgcn_cvt_pkrtz(a, b));
}

__device__ __forceinline__ int swz(int row) {
    return (row & 7) ^ ((2 * ((row >> 3) & 3)) & 7);
}

// ===========================================================================
// stage0: blocks 0..255 -> weight transpose (W fp32 [k][n] -> Wt f16 [n][k],
// wq scaled by 0.125*log2e). blocks 256..263 -> mask scan (idx, slen) +
// vt rank-pad zero-fill. The q/k/v cast is GONE -- proj_gemm consumes the
// fp32 activations directly via DMA staging.
// ===========================================================================
__global__ __launch_bounds__(256)
void stage0(const float* __restrict__ W0, const float* __restrict__ W1,
            const float* __restrict__ W2, const float* __restrict__ W3,
            f16* __restrict__ T0, f16* __restrict__ T1,
            f16* __restrict__ T2, f16* __restrict__ T3,
            const int* __restrict__ mask, int* __restrict__ idx,
            int* __restrict__ slen, f16* __restrict__ vt)
{
    __shared__ __align__(16) char sh[64 * 68 * 4];
    const int blk = blockIdx.x;
    const int tid = threadIdx.x;

    if (blk < 256) {
        float (*S)[68] = (float(*)[68])sh;
        const int z = blk >> 6, r2 = blk & 63;
        const float* W = (z==0)?W0:(z==1)?W1:(z==2)?W2:W3;
        f16*         T = (z==0)?T0:(z==1)?T1:(z==2)?T2:T3;
        const float sc = (z == 0) ? 0.125f * LOG2E : 1.0f;
        const int k0 = (r2 & 7) * 64, n0 = (r2 >> 3) * 64;
        {
            int kr = tid >> 4, nc = (tid & 15) * 4;
            #pragma unroll
            for (int i = 0; i < 4; ++i) {
                float4 w4 = *(const float4*)&W[(size_t)(k0 + kr + i*16) * Ez + n0 + nc];
                S[kr + i*16][nc+0] = w4.x; S[kr + i*16][nc+1] = w4.y;
                S[kr + i*16][nc+2] = w4.z; S[kr + i*16][nc+3] = w4.w;
            }
        }
        __syncthreads();
        {
            int n = tid >> 2, kq = tid & 3;
            f16 h[16];
            #pragma unroll
            for (int j = 0; j < 16; ++j) h[j] = (f16)(S[kq*16 + j][n] * sc);
            f16* dst = &T[(size_t)(n0 + n) * Ez + k0 + kq*16];
            *(uint4*)&dst[0] = *(uint4*)&h[0];
            *(uint4*)&dst[8] = *(uint4*)&h[8];
        }
        return;
    }

    const int b = blk - 256;
    if (b >= Bz) return;
    int (*sc2)[256] = (int(*)[256])sh;
    __shared__ int ssl;
    const int* mp = mask + (size_t)b * Sz;
    int m[8], c = 0;
    #pragma unroll
    for (int j = 0; j < 8; ++j) { m[j] = mp[tid*8 + j]; c += (m[j] == 0); }
    sc2[0][tid] = c;
    __syncthreads();
    int src = 0;
    #pragma unroll
    for (int s = 1; s < 256; s <<= 1) {
        int vv = sc2[src][tid] + ((tid >= s) ? sc2[src][tid - s] : 0);
        sc2[src ^ 1][tid] = vv;
        src ^= 1;
        __syncthreads();
    }
    int incl = sc2[src][tid];
    int base = incl - c;
    if (tid == 255) { slen[b] = incl; ssl = incl; }
    int kk = base;
    #pragma unroll
    for (int j = 0; j < 8; ++j)
        if (m[j] == 0) idx[(size_t)b * Sz + (kk++)] = tid*8 + j;
    __syncthreads();
    const int sl2 = ssl;
    const int pad = (sl2 + 63) & ~63;
    if (pad > sl2) {
        for (int pr = tid; pr < Hz * Dz; pr += 256) {
            f16* dst = vt + ((size_t)b * Hz * Dz + pr) * Sz;
            for (int j = sl2; j < pad; ++j) dst[j] = (f16)0.f;
        }
    }
}

// ===========================================================================
// proj_gemm: CAST-FUSED via DMA (not registers -- R10's mistake): the
// A-operand fp32 activation rows are global_load_lds'd DIRECTLY into LDS
// ([128][32] fp32, 16KB/buf; 8-chunk XOR swizzle chunk^(row&7) applied on
// the per-lane GLOBAL source, LDS dest linear). Fragments are read as
// 2x ds_read_b128 at positions p0=(2*quad)^(col&7), p1=p0^1 (2-way = free)
// and converted with cvt_pkrtz at use (same rounding as the old cast ->
// bit-identical). W stays on the f16 DMA path (8KB/buf). 48KB LDS,
// 3 blocks/CU. z==0: A = query, rows linear; z==1/2: A = key/value rows
// GATHERED by idx via per-lane DMA source; blocks past slen early-exit.
// Epilogue unchanged: z==0 -> qp; z==1 -> kp (rank < slen); z==2 -> V
// transposed in LDS then uint4 rank-run stores into vt, clipped at slen.
// Garbage ranks >= slen: K zeroed post-exp (select, NaN-proof) in attn;
// V clipped; vt pad pre-zeroed by stage0.
// ===========================================================================
__global__ __launch_bounds__(256, 3)
void proj_gemm(const float* __restrict__ Aq, const float* __restrict__ Ak,
               const float* __restrict__ Av,
               const f16* __restrict__ wtq, const f16* __restrict__ wtk,
               const f16* __restrict__ wtv,
               const float* __restrict__ bqp, const float* __restrict__ bkp,
               const float* __restrict__ bvp, const int* __restrict__ idx,
               const int* __restrict__ slen,
               f16* __restrict__ qp, f16* __restrict__ kp, f16* __restrict__ vt)
{
    __shared__ __align__(16) char lds[49152];   // 2 x (A fp32 16KB + W f16 8KB)
    const int z = blockIdx.z;
    const int m0 = blockIdx.x * 128, n0 = blockIdx.y * 128;
    const int bb = m0 >> 11;
    const int m0c = m0 & (Sz - 1);

    int sl = Sz;
    if (z != 0) {
        sl = slen[bb];
        if (m0c >= sl) return;      // uniform early-exit: tile fully past slen
    }

    const float* Af = (z==0)?Aq:(z==1)?Ak:Av;
    const f16* Wt = (z==0)?wtq:(z==1)?wtk:wtv;
    const float* bias = (z==0)?bqp:(z==1)?bkp:bvp;
    const float bscale = (z==0) ? 0.125f*LOG2E : 1.0f;

    const int tid  = threadIdx.x;
    const int lane = tid & 63, w = tid >> 6;
    const int col  = lane & 15, quad = lane >> 4;
    const int wm = w & 1, wn = w >> 1;
    const int srow = lane >> 2, schunk = lane & 3;   // W staging (16B f16 chunks)
    const int arow8 = lane >> 3, achk = lane & 7;    // A staging (16B fp32 chunks)

    // per-thread A source row bases (fp32, rank-gathered for K/V), 4 rows/thread
    size_t rbA[4];
    int acs[4];                                      // swizzled source chunk
    #pragma unroll
    for (int i = 0; i < 4; ++i) {
        const int row = w*32 + i*8 + arow8;
        acs[i] = achk ^ (row & 7);
        int srcrow;
        if (z == 0) {
            srcrow = m0 + row;                       // global row in [0,16384)
            rbA[i] = (size_t)srcrow * Ez;
        } else {
            const int j = m0c + row;
            const int jc = (j < sl) ? j : sl - 1;
            srcrow = idx[(size_t)bb * Sz + jc];
            rbA[i] = ((size_t)bb * Sz + srcrow) * Ez;
        }
    }

    f32x4 acc[4][4];
    #pragma unroll
    for (int i = 0; i < 4; ++i)
        #pragma unroll
        for (int j = 0; j < 4; ++j) acc[i][j] = (f32x4){0.f,0.f,0.f,0.f};

    auto issue = [&](int t, int buf) {
        float* As32 = (float*)(lds + buf * 24576);
        f16*   Ws   = (f16*)(lds + buf * 24576 + 16384);
        #pragma unroll
        for (int i = 0; i < 4; ++i) {
            const int row = w*32 + i*8 + arow8;
            async16(&Af[rbA[i] + t*32 + acs[i]*4], &As32[row*32 + achk*4]);
        }
        #pragma unroll
        for (int i = 0; i < 2; ++i) {
            const int row = w*32 + i*16 + srow;
            const int cl = schunk ^ ((row >> 1) & 3);
            async16(&Wt[(size_t)(n0 + row) * Ez + t*32 + cl*8], &Ws[row*32 + schunk*8]);
        }
    };

    issue(0, 0);
    const int xrc = (col >> 1) & 3;
    const int p0 = (quad * 2) ^ (col & 7), p1 = p0 ^ 1;

    for (int t = 0; t < 16; ++t) {
        const int cur = t & 1;
        __syncthreads();
        if (t < 15) issue(t + 1, cur ^ 1);
        float* As32 = (float*)(lds + cur * 24576);
        f16*   Ws   = (f16*)(lds + cur * 24576 + 16384);
        f16x8 af[4];
        #pragma unroll
        for (int mi = 0; mi < 4; ++mi) {
            const int r = wm*64 + mi*16 + col;
            float4 a0 = *(const float4*)&As32[r*32 + p0*4];
            float4 a1 = *(const float4*)&As32[r*32 + p1*4];
            union { f16x2 h2[4]; f16x8 h8; } ua;
            ua.h2[0] = pkrtz(a0.x, a0.y);
            ua.h2[1] = pkrtz(a0.z, a0.w);
            ua.h2[2] = pkrtz(a1.x, a1.y);
            ua.h2[3] = pkrtz(a1.z, a1.w);
            af[mi] = ua.h8;
        }
        #pragma unroll
        for (int ni = 0; ni < 4; ++ni) {
            f16x8 wf = *(const f16x8*)&Ws[(wn*64 + ni*16 + col)*32 + ((quad ^ xrc)*8)];
            #pragma unroll
            for (int mi = 0; mi < 4; ++mi)
                acc[mi][ni] = __builtin_amdgcn_mfma_f32_16x16x32_f16(af[mi], wf, acc[mi][ni], 0,0,0);
        }
    }

    const int rw = tid >> 1, half = tid & 1;

    f16* Tr  = (f16*)lds;    // z<2:  [128][72] row-major (m, d)
    f16* Tr2 = (f16*)lds;    // z==2: [64][136] transposed (d, m)
    #pragma unroll
    for (int p = 0; p < 2; ++p) {
        __syncthreads();
        if (wn == p) {
            #pragma unroll
            for (int ni = 0; ni < 4; ++ni) {
                float bv = bias[n0 + p*64 + ni*16 + col] * bscale;
                #pragma unroll
                for (int mi = 0; mi < 4; ++mi)
                    #pragma unroll
                    for (int rr = 0; rr < 4; ++rr) {
                        const int ml = wm*64 + mi*16 + quad*4 + rr;
                        const float val = acc[mi][ni][rr] + bv;
                        if (z != 2) Tr[ml*72 + ni*16 + col] = (f16)val;
                        else        Tr2[(ni*16 + col)*136 + ml] = (f16)val;
                    }
            }
        }
        __syncthreads();
        const int hh = (n0 >> 6) + p;
        if (z != 2) {
            const int rank = m0c + rw;
            if (z == 0 || rank < sl) {
                f16* C16 = (z == 0) ? qp : kp;
                f16* dst = &C16[(((size_t)bb*Hz + hh)*Sz + rank)*Dz + half*32];
                const f16* srcp = &Tr[rw*72 + half*32];
                #pragma unroll
                for (int j = 0; j < 4; ++j)
                    *(uint4*)&dst[j*8] = *(const uint4*)&srcp[j*8];
            }
        } else {
            const int d = tid >> 2, mq = tid & 3;
            const int base = m0c + mq*32;
            if (base < sl) {
                f16* dstb = vt + (((size_t)bb*Hz + hh)*Dz + d)*Sz + base;
                const f16* srcr = &Tr2[d*136 + mq*32];
                int lim = sl - base; if (lim > 32) lim = 32;
                if (lim == 32) {
                    #pragma unroll
                    for (int g = 0; g < 4; ++g)
                        *(uint4*)&dstb[g*8] = *(const uint4*)&srcr[g*8];
                } else {
                    const int full = lim >> 3;
                    for (int g = 0; g < full; ++g)
                        *(uint4*)&dstb[g*8] = *(const uint4*)&srcr[g*8];
                    for (int e = full*8; e < lim; ++e) dstb[e] = srcr[e];
                }
            }
        }
    }
}

// ===========================================================================
// out_gemm: DOUBLE-buffered staging, 128x128 tile, fp32 row-major + bias.
// ===========================================================================
__global__ __launch_bounds__(256, 4)
void out_gemm(const f16* __restrict__ A, const f16* __restrict__ Wt,
              const float* __restrict__ bias, float* __restrict__ Cf)
{
    __shared__ __align__(16) char lds[32768];
    const int tid  = threadIdx.x;
    const int lane = tid & 63, w = tid >> 6;
    const int col  = lane & 15, quad = lane >> 4;
    const int wm = w & 1, wn = w >> 1;
    const int m0 = blockIdx.x * 128, n0 = blockIdx.y * 128;
    const int srow = lane >> 2, schunk = lane & 3;

    f32x4 acc[4][4];
    #pragma unroll
    for (int i = 0; i < 4; ++i)
        #pragma unroll
        for (int j = 0; j < 4; ++j) acc[i][j] = (f32x4){0.f,0.f,0.f,0.f};

    auto issue = [&](int t, int buf) {
        f16* As = (f16*)(lds + buf * 16384);
        f16* Ws = As + 4096;
        #pragma unroll
        for (int i = 0; i < 2; ++i) {
            int row = w*32 + i*16 + srow;
            int cl = schunk ^ ((row >> 1) & 3);
            async16(&A[(size_t)(m0 + row) * Ez + t*32 + cl*8],  &As[row*32 + schunk*8]);
            async16(&Wt[(size_t)(n0 + row) * Ez + t*32 + cl*8], &Ws[row*32 + schunk*8]);
        }
    };

    issue(0, 0);
    const int xrc = (col >> 1) & 3;

    for (int t = 0; t < 16; ++t) {
        const int cur = t & 1;
        __syncthreads();
        if (t < 15) issue(t + 1, cur ^ 1);
        f16* As = (f16*)(lds + cur * 16384);
        f16* Ws = As + 4096;
        f16x8 af[4];
        #pragma unroll
        for (int mi = 0; mi < 4; ++mi)
            af[mi] = *(const f16x8*)&As[(wm*64 + mi*16 + col)*32 + ((quad ^ xrc)*8)];
        #pragma unroll
        for (int ni = 0; ni < 4; ++ni) {
            f16x8 wf = *(const f16x8*)&Ws[(wn*64 + ni*16 + col)*32 + ((quad ^ xrc)*8)];
            #pragma unroll
            for (int mi = 0; mi < 4; ++mi)
                acc[mi][ni] = __builtin_amdgcn_mfma_f32_16x16x32_f16(af[mi], wf, acc[mi][ni], 0,0,0);
        }
    }

    #pragma unroll
    for (int ni = 0; ni < 4; ++ni) {
        int n = n0 + wn*64 + ni*16 + col;
        float bv = bias[n];
        #pragma unroll
        for (int mi = 0; mi < 4; ++mi)
            #pragma unroll
            for (int rr = 0; rr < 4; ++rr) {
                int m = m0 + wm*64 + mi*16 + quad*4 + rr;
                Cf[(size_t)m * Ez + n] = acc[mi][ni][rr] + bv;
            }
    }
}

// ===========================================================================
// Flash attention over compacted keys (R2 structure: double-buffer +
// __syncthreads drain; 32KB LDS, 4 blocks/CU). K pre-compacted; V
// pre-transposed and pad-zeroed, so tail P-zeroing keeps everything exact.
// ===========================================================================
__global__ __launch_bounds__(256, 4)
void attn_f16(const f16* __restrict__ Q, const f16* __restrict__ K,
              const f16* __restrict__ VT, const int* __restrict__ slen,
              f16* __restrict__ O)
{
    __shared__ __align__(16) f16 KS[2][64*64];
    __shared__ __align__(16) f16 VS[2][64*64];

    const int tid  = threadIdx.x;
    const int lane = tid & 63, w = tid >> 6;
    const int col  = lane & 15, quad = lane >> 4;

    const int blk = blockIdx.x;
    const int xcd = blk & 7, slot = blk >> 3;
    const int bh = xcd + 8 * (slot >> 4);
    const int qb = slot & 15;
    const int b = bh >> 3, h = bh & 7;

    const int sl = slen[b];
    int nt = (sl + 63) >> 6;
    if (nt < 1) nt = 1;

    const int q0 = qb * 128 + w * 32;

    f16x8 qf[2][2];
    #pragma unroll
    for (int qt = 0; qt < 2; ++qt)
        #pragma unroll
        for (int ks = 0; ks < 2; ++ks)
            qf[qt][ks] = *(const f16x8*)&Q[((size_t)bh*Sz + q0 + qt*16 + col)*Dz + ks*32 + quad*8];

    const f16* Kp = K + (size_t)bh * Sz * Dz;
    const f16* Vp = VT + (size_t)bh * Dz * Sz;

    const int srow = lane >> 3, sch = lane & 7;
    const int row0 = w*16 + srow, row1 = row0 + 8;
    const int cl0 = sch ^ swz(row0), cl1 = sch ^ swz(row1);

    int keyrow[4], gk[4];
    #pragma unroll
    for (int kc = 0; kc < 4; ++kc) {
        keyrow[kc] = 32*(kc>>1) + 8*(col>>2) + 4*(kc&1) + (col&3);
        gk[kc] = swz(keyrow[kc]);
    }

    f32x4 oacc[2][4];
    #pragma unroll
    for (int qt = 0; qt < 2; ++qt)
        #pragma unroll
        for (int dc = 0; dc < 4; ++dc) oacc[qt][dc] = (f32x4){0.f,0.f,0.f,0.f};
    const f32x4 zero4 = (f32x4){0.f, 0.f, 0.f, 0.f};
    f32x4 lacc[2] = {(f32x4){0.f,0.f,0.f,0.f}, (f32x4){0.f,0.f,0.f,0.f}};
    f16x8 one8;
    #pragma unroll
    for (int i = 0; i < 8; ++i) one8[i] = (f16)1.0f;

    auto issue = [&](int t, int buf) {
        async16(&Kp[(size_t)(t*64 + row0)*Dz + cl0*8], &KS[buf][row0*64 + sch*8]);
        async16(&Vp[(size_t)row0*Sz + t*64 + cl0*8],   &VS[buf][row0*64 + sch*8]);
        async16(&Kp[(size_t)(t*64 + row1)*Dz + cl1*8], &KS[buf][row1*64 + sch*8]);
        async16(&Vp[(size_t)row1*Sz + t*64 + cl1*8],   &VS[buf][row1*64 + sch*8]);
    };

    issue(0, 0);

    for (int t = 0; t < nt; ++t) {
        const int cur = t & 1;
        __syncthreads();
        if (t + 1 < nt) issue(t + 1, cur ^ 1);

        // ---- QK^T: S^T = K·Q^T (C initialized from persistent zero regs)
        f32x4 sc[2][4];
        __builtin_amdgcn_s_setprio(1);
        #pragma unroll
        for (int kc = 0; kc < 4; ++kc) {
            f16x8 kf0 = *(const f16x8*)&KS[cur][keyrow[kc]*64 + ((quad ^ gk[kc])*8)];
            f16x8 kf1 = *(const f16x8*)&KS[cur][keyrow[kc]*64 + (((4 + quad) ^ gk[kc])*8)];
            sc[0][kc] = __builtin_amdgcn_mfma_f32_16x16x32_f16(kf0, qf[0][0], zero4, 0,0,0);
            sc[1][kc] = __builtin_amdgcn_mfma_f32_16x16x32_f16(kf0, qf[1][0], zero4, 0,0,0);
            sc[0][kc] = __builtin_amdgcn_mfma_f32_16x16x32_f16(kf1, qf[0][1], sc[0][kc], 0,0,0);
            sc[1][kc] = __builtin_amdgcn_mfma_f32_16x16x32_f16(kf1, qf[1][1], sc[1][kc], 0,0,0);
        }
        __builtin_amdgcn_s_setprio(0);

        // ---- p = exp2(s) (raw v_exp_f32); zero tail on last tile (select is
        // NaN-proof for garbage K rows); pack B-frags
        const bool last = (t == nt - 1);
        union { f16x2 h2[4]; f16x8 h8; } ph[2][2];
        #pragma unroll
        for (int qt = 0; qt < 2; ++qt) {
            #pragma unroll
            for (int kg = 0; kg < 2; ++kg) {
                float e0 = __builtin_amdgcn_exp2f(sc[qt][2*kg][0]);
                float e1 = __builtin_amdgcn_exp2f(sc[qt][2*kg][1]);
                float e2 = __builtin_amdgcn_exp2f(sc[qt][2*kg][2]);
                float e3 = __builtin_amdgcn_exp2f(sc[qt][2*kg][3]);
                float e4 = __builtin_amdgcn_exp2f(sc[qt][2*kg+1][0]);
                float e5 = __builtin_amdgcn_exp2f(sc[qt][2*kg+1][1]);
                float e6 = __builtin_amdgcn_exp2f(sc[qt][2*kg+1][2]);
                float e7 = __builtin_amdgcn_exp2f(sc[qt][2*kg+1][3]);
                if (last) {
                    int rem = sl - t*64 - 32*kg - 8*quad;
                    e0 = (rem > 0) ? e0 : 0.f; e1 = (rem > 1) ? e1 : 0.f;
                    e2 = (rem > 2) ? e2 : 0.f; e3 = (rem > 3) ? e3 : 0.f;
                    e4 = (rem > 4) ? e4 : 0.f; e5 = (rem > 5) ? e5 : 0.f;
                    e6 = (rem > 6) ? e6 : 0.f; e7 = (rem > 7) ? e7 : 0.f;
                }
                ph[qt][kg].h2[0] = pkrtz(e0, e1);
                ph[qt][kg].h2[1] = pkrtz(e2, e3);
                ph[qt][kg].h2[2] = pkrtz(e4, e5);
                ph[qt][kg].h2[3] = pkrtz(e6, e7);
            }
        }

        // ---- lsum (ones-row MFMA) + PV: O^T += V^T·P^T
        __builtin_amdgcn_s_setprio(1);
        lacc[0] = __builtin_amdgcn_mfma_f32_16x16x32_f16(one8, ph[0][0].h8, lacc[0], 0,0,0);
        lacc[1] = __builtin_amdgcn_mfma_f32_16x16x32_f16(one8, ph[1][0].h8, lacc[1], 0,0,0);
        lacc[0] = __builtin_amdgcn_mfma_f32_16x16x32_f16(one8, ph[0][1].h8, lacc[0], 0,0,0);
        lacc[1] = __builtin_amdgcn_mfma_f32_16x16x32_f16(one8, ph[1][1].h8, lacc[1], 0,0,0);
        #pragma unroll
        for (int dc = 0; dc < 4; ++dc) {
            const int d = dc*16 + col;
            const int gd = swz(d);
            #pragma unroll
            for (int kg = 0; kg < 2; ++kg) {
                f16x8 vf = *(const f16x8*)&VS[cur][d*64 + (((kg*4 + quad) ^ gd)*8)];
                oacc[0][dc] = __builtin_amdgcn_mfma_f32_16x16x32_f16(vf, ph[0][kg].h8, oacc[0][dc], 0,0,0);
                oacc[1][dc] = __builtin_amdgcn_mfma_f32_16x16x32_f16(vf, ph[1][kg].h8, oacc[1][dc], 0,0,0);
            }
        }
        __builtin_amdgcn_s_setprio(0);
    }

    // lacc rows are identical (A = ones) -> no cross-lane reduce needed;
    // col = lane&15 matches oacc's query mapping.
    float inv[2];
    inv[0] = 1.0f / lacc[0][0];
    inv[1] = 1.0f / lacc[1][0];
    #pragma unroll
    for (int qt = 0; qt < 2; ++qt) {
        const int q = q0 + qt*16 + col;
        f16* op = &O[((size_t)b*Sz + q)*Ez + h*Dz];
        #pragma unroll
        for (int dc = 0; dc < 4; ++dc) {
            f16 ov[4] = {(f16)(oacc[qt][dc][0]*inv[qt]), (f16)(oacc[qt][dc][1]*inv[qt]),
                         (f16)(oacc[qt][dc][2]*inv[qt]), (f16)(oacc[qt][dc][3]*inv[qt])};
            *(uint2*)&op[dc*16 + quad*4] = *(uint2*)ov;
        }
    }
}

// ===========================================================================
extern "C" void kernel_launch(void* const* d_in, const int* in_sizes, int n_in,
                              void* d_out, int out_size, void* d_ws, size_t ws_size,
                              hipStream_t stream)
{
    const float* value = (const float*)d_in[0];
    const float* key   = (const float*)d_in[1];
    const float* query = (const float*)d_in[2];
    const int*   mask  = (const int*)d_in[3];
    const float* wq = (const float*)d_in[4];
    const float* bq = (const float*)d_in[5];
    const float* wk = (const float*)d_in[6];
    const float* bk = (const float*)d_in[7];
    const float* wv = (const float*)d_in[8];
    const float* bv = (const float*)d_in[9];
    const float* wo = (const float*)d_in[10];
    const float* bo = (const float*)d_in[11];
    float* out = (float*)d_out;

    const size_t nW   = (size_t)Ez * Ez;             // 262144
    const size_t nAct = (size_t)Bz * Sz * Ez;        // 8388608
    f16* wtq = (f16*)d_ws;
    f16* wtk = wtq + nW;
    f16* wtv = wtk + nW;
    f16* wto = wtv + nW;
    f16* qp  = wto + nW;
    f16* kp  = qp + nAct;
    f16* vt  = kp + nAct;
    f16* o16 = vt + nAct;
    int* idxp = (int*)(o16 + nAct);
    int* slenp = idxp + Bz * Sz;

    stage0<<<264, 256, 0, stream>>>(wq, wk, wv, wo, wtq, wtk, wtv, wto,
                                    mask, idxp, slenp, vt);

    proj_gemm<<<dim3(128, 4, 3), 256, 0, stream>>>(query, key, value,
                                                   wtq, wtk, wtv,
                                                   bq, bk, bv, idxp, slenp,
                                                   qp, kp, vt);

    attn_f16<<<1024, 256, 0, stream>>>(qp, kp, vt, slenp, o16);

    out_gemm<<<dim3(128, 4), 256, 0, stream>>>(o16, wto, bo, out);
}